// Round 4
// baseline (1158.984 us; speedup 1.0000x reference)
//
#include <hip/hip_runtime.h>
#include <hip/hip_bf16.h>

// Dipole: day-emb GEMM -> fwd GRU + 64 reverse GRUs -> masked softmax attention -> 2-layer head.
// T=64 B=32 D_IN=4096 D_DAY=H=256 D_OUT=942.
//
//  k1 pack_all      : repack GEMM weights to bf16 MFMA B-fragment layout.
//                     Wih r,z rows pre-scaled by -log2e; n rows by 2*log2e (exp2-form gates).
//  k1b pack_hh_i8   : Whh -> int8 per-row-scaled MFMA B-frags (i8 16x16x64).
//  k1c prep_bias    : bias_comb[1536], same gate pre-scaling.
//  k2 gemm<0>       : day_emb = x @ W_emb^T + b_emb  (NTILES=8: x read once per 2 n-blocks)
//  k3 gemm<1>       : Git = day_emb @ Wih^T + bias   (bf16 [dir][t][g][d][b]; LDS-transpose
//                     epilogue -> coalesced b128 stores. R3 failure: 16 scalar stores/thread
//                     at 64B stride = 3% line efficiency on a 6MB tensor)
//  k4 gru_recurrent : 128 reverse WGs + 2 forward WGs; 1024 thr/16 waves; int8 MFMA;
//                     NO hist LDS (direct fire-and-forget global stores; lgkm-only barrier
//                     never drains vmcnt); depth-2 Git register prefetch.
//  k5 attn          : per-(i,b) wave online softmax, 1-deep load prefetch.
//  k6 gemm<2>       : tmp = h_t @ W_ao^T + b_ao
//  k7 gemm<3>       : out = sigmoid(tmp @ W_o^T + b_o)

typedef __bf16 bf16x8 __attribute__((ext_vector_type(8)));
typedef __bf16 bf16x4 __attribute__((ext_vector_type(4)));
typedef float  f32x4  __attribute__((ext_vector_type(4)));
typedef int    int4v  __attribute__((ext_vector_type(4)));

static constexpr float NEG_L2E = -1.442695041f;   // -log2(e)
static constexpr float TWO_L2E =  2.885390082f;   //  2*log2(e)

// ---------------- workspace layout (bytes) ----------------
static constexpr size_t OFF_PK_EMB = 0;                        // 256x4096 bf16    = 2097152
static constexpr size_t OFF_PK_IH  = 2097152;                  // 1536x256 bf16    =  786432
static constexpr size_t OFF_WQ     = 2883584;                  // 2x768x256 int8   =  393216
static constexpr size_t OFF_WSC    = 3276800;                  // 1536 f32         =    6144
static constexpr size_t OFF_PK_AO  = 3670016;                  // 256x1024 bf16    =  524288
static constexpr size_t OFF_PK_O   = 4194304;                  // 960x256 bf16     =  491520
static constexpr size_t OFF_DAY    = 4685824;                  // 2048x256 bf16    = 1048576
static constexpr size_t OFF_GIT    = 5734400;                  // 2*64*3*256*32 bf16 = 6291456
static constexpr size_t OFF_BC     = 12025856;                 // 1536 f32         =    6144
static constexpr size_t OFF_REV    = 18317312;                 // 2080*32*256 bf16 = 34078720
static constexpr size_t OFF_FWD    = 52396032;                 // 64*32*256 bf16   = 1048576
static constexpr size_t OFF_HT     = 53444608;                 // 2048x1024 bf16   = 4194304
static constexpr size_t OFF_TMP1   = 57638912;                 // 2048x256 bf16    = 1048576

__device__ __forceinline__ float sigf(float x) {
    return __builtin_amdgcn_rcpf(1.f + __expf(-x));
}

// lgkmcnt-only barrier: does NOT drain vmcnt (global stores stay in flight).
#define LDS_BARRIER() asm volatile("s_waitcnt lgkmcnt(0)\n\ts_barrier" ::: "memory")

// ---------------- bf16 weight packer (GEMM weights) ----------------
// frag layout: flat = ((nt*K32 + ks)*64 + lane)*8 + j holds W[nt*16+lane%16][ks*32+(lane/16)*8+j]
__global__ __launch_bounds__(256) void pack_all(
    const float* __restrict__ We,  const float* __restrict__ Wir, const float* __restrict__ Wif,
    const float* __restrict__ Wao, const float* __restrict__ Wo,
    __bf16* pe, __bf16* pi, __bf16* pao, __bf16* po)
{
    int b = blockIdx.x;
    const float* src; __bf16* dst; int Nsrc, k32l, b0; bool ih = false;
    if (b < 4096)      { src = We;  dst = pe;          Nsrc = 256; k32l = 7; b0 = 0;    }
    else if (b < 4864) { src = Wir; dst = pi;          Nsrc = 768; k32l = 3; b0 = 4096; ih = true; }
    else if (b < 5632) { src = Wif; dst = pi + 196608; Nsrc = 768; k32l = 3; b0 = 4864; ih = true; }
    else if (b < 6656) { src = Wao; dst = pao;         Nsrc = 256; k32l = 5; b0 = 5632; }
    else               { src = Wo;  dst = po;          Nsrc = 942; k32l = 3; b0 = 6656; }
    int e    = (b - b0) * 256 + threadIdx.x;
    int j    = e & 7;
    int lane = (e >> 3) & 63;
    int K32  = 1 << k32l;
    int K    = K32 << 5;
    int ks   = (e >> 9) & (K32 - 1);
    int nt   = e >> (9 + k32l);
    int n    = nt * 16 + (lane & 15);
    int k    = ks * 32 + ((lane >> 4) << 3) + j;
    float v  = (n < Nsrc) ? src[(size_t)n * K + k] : 0.f;
    if (ih) v *= (n < 512) ? NEG_L2E : TWO_L2E;   // exp2-form gate pre-scaling
    dst[e] = (__bf16)v;
}

// ---------------- Whh int8 packer ----------------
// i8 16x16x64 B-frag: (n,k): lane = (n&15)|(((k>>4)&3)<<4), byte j = k&15;
// flat = dir*196608 + ((n>>4)*4 + (k>>6))*1024 + lane*16 + j.  scale[dir*768+n] = rowmax/127.
__global__ __launch_bounds__(64) void pack_hh_i8(
    const float* __restrict__ Whr, const float* __restrict__ Whf,
    signed char* __restrict__ wq, float* __restrict__ wscale)
{
    int b = blockIdx.x;               // 1536: dir*768 + n
    int dir = (b >= 768) ? 1 : 0;
    int n = b - dir * 768;
    const float* src = (dir ? Whf : Whr) + (size_t)n * 256;
    int t = threadIdx.x;
    float4 wv = ((const float4*)src)[t];
    float m = fmaxf(fmaxf(fabsf(wv.x), fabsf(wv.y)), fmaxf(fabsf(wv.z), fabsf(wv.w)));
#pragma unroll
    for (int off = 32; off > 0; off >>= 1) m = fmaxf(m, __shfl_xor(m, off));
    float s_step = m * (1.f / 127.f);
    float inv = 127.f / m;
    int q0 = (int)__builtin_rintf(wv.x * inv);
    int q1 = (int)__builtin_rintf(wv.y * inv);
    int q2 = (int)__builtin_rintf(wv.z * inv);
    int q3 = (int)__builtin_rintf(wv.w * inv);
    int pk = (q0 & 0xff) | ((q1 & 0xff) << 8) | ((q2 & 0xff) << 16) | ((q3 & 0xff) << 24);
    int dlane = (n & 15) | (((t >> 2) & 3) << 4);
    size_t byte = (size_t)dir * 196608 + ((size_t)(n >> 4) * 4 + (t >> 4)) * 1024
                + (size_t)dlane * 16 + (t & 3) * 4;
    *(int*)(wq + byte) = pk;
    if (t == 0) wscale[b] = s_step;
}

// bias_comb[n]: dir = n>=768; rem<512: (bih+bhh)*(-log2e); rem in [512,768): bih*2log2e
__global__ __launch_bounds__(256) void prep_bias(
    const float* __restrict__ bih_r, const float* __restrict__ bhh_r,
    const float* __restrict__ bih_f, const float* __restrict__ bhh_f,
    float* __restrict__ bc)
{
    int n = blockIdx.x * 256 + threadIdx.x;
    if (n >= 1536) return;
    int dir = (n >= 768) ? 1 : 0;
    int rem = n - dir * 768;
    const float* bi = dir ? bih_f : bih_r;
    const float* bh = dir ? bhh_f : bhh_r;
    float v;
    if (rem < 512) v = (bi[rem] + bh[rem]) * NEG_L2E;
    else           v = bi[rem] * TWO_L2E;
    bc[n] = v;
}

// ---------------- generic MFMA GEMM: C[M x N] = A[M x K] @ W^T (+bias) ----------------
// MODE 0: A fp32, out bf16 row-major. MODE 1: A bf16, out bf16 Git (LDS-transposed epilogue).
// MODE 2: A bf16, out bf16 row-major. MODE 3: A bf16, out fp32 sigmoid masked to NREAL.
template<int MODE, int KDIM, int NTILES, int CSTRIDE, int NREAL>
__global__ __launch_bounds__(256) void gemm_k(
    const void* __restrict__ Ap, const __bf16* __restrict__ Bp, void* __restrict__ Cp,
    const float* __restrict__ bias)
{
    __shared__ __align__(16) __bf16 As[64][88];
    const int tid = threadIdx.x;
    const int w = tid >> 6, lane = tid & 63, c = lane & 15, quad = lane >> 4;
    const int mb = blockIdx.x, nb = blockIdx.y;
    constexpr int K32 = KDIM / 32;
    constexpr int NK  = KDIM / 64;

    f32x4 acc[NTILES];
#pragma unroll
    for (int nt = 0; nt < NTILES; nt++) acc[nt] = (f32x4){0.f, 0.f, 0.f, 0.f};

    const int row = tid >> 2, kp = (tid & 3) * 16;
    float4 pf[4]; uint4 pb[2];

    auto issue = [&](int kb) {
        if constexpr (MODE == 0) {
            const float* ap = (const float*)Ap + (size_t)(mb * 64 + row) * KDIM + kb * 64 + kp;
            pf[0] = ((const float4*)ap)[0]; pf[1] = ((const float4*)ap)[1];
            pf[2] = ((const float4*)ap)[2]; pf[3] = ((const float4*)ap)[3];
        } else {
            const __bf16* ap = (const __bf16*)Ap + (size_t)(mb * 64 + row) * KDIM + kb * 64 + kp;
            pb[0] = ((const uint4*)ap)[0]; pb[1] = ((const uint4*)ap)[1];
        }
    };
    auto commit = [&]() {
        if constexpr (MODE == 0) {
            __bf16 t[16];
#pragma unroll
            for (int q = 0; q < 4; q++) {
                t[q*4+0] = (__bf16)pf[q].x; t[q*4+1] = (__bf16)pf[q].y;
                t[q*4+2] = (__bf16)pf[q].z; t[q*4+3] = (__bf16)pf[q].w;
            }
            *(uint4*)&As[row][kp]     = *(uint4*)&t[0];
            *(uint4*)&As[row][kp + 8] = *(uint4*)&t[8];
        } else {
            *(uint4*)&As[row][kp]     = pb[0];
            *(uint4*)&As[row][kp + 8] = pb[1];
        }
    };

    issue(0);
    for (int kb = 0; kb < NK; kb++) {
        commit();
        __syncthreads();
        if (kb + 1 < NK) issue(kb + 1);
#pragma unroll
        for (int kk = 0; kk < 2; kk++) {
            bf16x8 a = *(const bf16x8*)&As[w * 16 + c][kk * 32 + quad * 8];
#pragma unroll
            for (int nt = 0; nt < NTILES; nt++) {
                bf16x8 bfr = *(const bf16x8*)(Bp +
                    ((size_t)((nb * NTILES + nt) * K32 + kb * 2 + kk) * 64 + lane) * 8);
                acc[nt] = __builtin_amdgcn_mfma_f32_16x16x32_bf16(a, bfr, acc[nt], 0, 0, 0);
            }
        }
        __syncthreads();
    }

    if constexpr (MODE == 1) {
        // transpose epilogue: acc -> As[n_local][m_local] (stride 88), then coalesced b128
        // stores of the [d][b] plane per t.
#pragma unroll
        for (int nt = 0; nt < NTILES; nt++) {
            int n = nb * (NTILES * 16) + nt * 16 + c;
            float bv = bias[n];
#pragma unroll
            for (int r0 = 0; r0 < 4; r0++)
                As[nt * 16 + c][w * 16 + quad * 4 + r0] = (__bf16)(acc[nt][r0] + bv);
        }
        __syncthreads();
        const int dir = nb / 12, rem = nb % 12;
        const int g = rem >> 2, d0 = (rem & 3) * 64;
        const int dd = tid >> 2, bch = tid & 3;
#pragma unroll
        for (int tl = 0; tl < 2; tl++) {
            uint4 v = *(const uint4*)&As[dd][tl * 32 + bch * 8];
            size_t off = (((size_t)((dir * 64 + mb * 2 + tl) * 3 + g) * 256) + d0 + dd) * 32
                       + bch * 8;
            *(uint4*)((__bf16*)Cp + off) = v;
        }
    } else {
#pragma unroll
        for (int nt = 0; nt < NTILES; nt++) {
            int n = nb * (NTILES * 16) + nt * 16 + c;
            float bv = (n < NREAL) ? bias[n] : 0.f;
#pragma unroll
            for (int r0 = 0; r0 < 4; r0++) {
                int m = mb * 64 + w * 16 + quad * 4 + r0;
                float v = acc[nt][r0] + bv;
                if constexpr (MODE == 0)      ((__bf16*)Cp)[(size_t)m * CSTRIDE + n] = (__bf16)v;
                else if constexpr (MODE == 2) ((__bf16*)Cp)[(size_t)m * CSTRIDE + n] = (__bf16)v;
                else { if (n < NREAL) ((float*)Cp)[(size_t)m * CSTRIDE + n] = sigf(v); }
            }
        }
    }
}

// ---------------- recurrent GRU kernel ----------------
// grid = 130 x 1024 (16 waves). bid 0/1: forward halves; bid 2..129: reverse, longest-first.
// Wave w owns 16 dims x 3 gates; Whh int8 frags (48 regs -> AGPR). Gates in exp2 form
// (constants pre-folded). Direct global h stores (never waited); depth-2 Git prefetch.
__global__ __launch_bounds__(1024, 4) void gru_recurrent(
    const signed char* __restrict__ wq, const float* __restrict__ wscale,
    const float* __restrict__ bhh_r, const float* __restrict__ bhh_f,
    const __bf16* __restrict__ Git,
    __bf16* __restrict__ revb, __bf16* __restrict__ fwdb)
{
    __shared__ __align__(16) signed char hbuf[2][16][272];
    const int tid = threadIdx.x;
    const int w = tid >> 6, lane = tid & 63, c = lane & 15, quad = lane >> 4;
    const int bid = blockIdx.x;
    const bool isF = (bid < 2);
    const int ia = isF ? 63 : (63 - ((bid - 2) >> 1));
    const int b0 = (bid & 1) << 4;
    const int steps = ia + 1;
    const float* bhh = isF ? bhh_f : bhh_r;
    __bf16* outb = isF ? fwdb : (revb + ((size_t)(ia * (ia + 1) / 2)) * 8192);

    const int4v* pw = (const int4v*)(wq + (isF ? 196608 : 0));
    int4v bw[3][4];
#pragma unroll
    for (int g = 0; g < 3; g++)
#pragma unroll
        for (int ks = 0; ks < 4; ks++)
            bw[g][ks] = pw[(size_t)((g * 16 + w) * 4 + ks) * 64 + lane];
    const int d = (w << 4) + c;
    float sc[3];
    sc[0] = wscale[(isF ? 768 : 0) + d]       * (NEG_L2E / 127.f);
    sc[1] = wscale[(isF ? 768 : 0) + 256 + d] * (NEG_L2E / 127.f);
    sc[2] = wscale[(isF ? 768 : 0) + 512 + d] * (TWO_L2E / 127.f);
    const float bnv = bhh[512 + d] * TWO_L2E;

    float hreg[4] = {0.f, 0.f, 0.f, 0.f};
    for (int idx = tid; idx < 2 * 16 * 272 / 4; idx += 1024) ((int*)hbuf)[idx] = 0;
    __syncthreads();

    // Git[dir][t][g][d][b]; reverse walks t = ia..0, forward t = 0..63
    const __bf16* gb = Git + (size_t)(isF ? 64 : ia) * 24576 + b0 + (quad << 2);
    const long gstep = isF ? 24576 : -24576;
    __bf16* go = outb + (size_t)(b0 + (quad << 2)) * 256 + d;

    bf16x4 gbuf[2][3];
    auto gload = [&](int slot, const __bf16* p) {
#pragma unroll
        for (int g = 0; g < 3; g++)
            gbuf[slot][g] = *(const bf16x4*)(p + ((size_t)((g << 8) + d) << 5));
    };
    gload(0, gb);
    if (steps > 1) gload(1, gb + gstep);

    for (int j = 0; j < steps; j++) {
        const int rb = j & 1, wbuf = rb ^ 1;

        int4v a0 = {0,0,0,0}, a1 = {0,0,0,0}, a2 = {0,0,0,0};
#pragma unroll
        for (int ks = 0; ks < 4; ks++) {
            int4v av = *(const int4v*)&hbuf[rb][c][ks * 64 + quad * 16];
            a0 = __builtin_amdgcn_mfma_i32_16x16x64_i8(av, bw[0][ks], a0, 0, 0, 0);
            a1 = __builtin_amdgcn_mfma_i32_16x16x64_i8(av, bw[1][ks], a1, 0, 0, 0);
            a2 = __builtin_amdgcn_mfma_i32_16x16x64_i8(av, bw[2][ks], a2, 0, 0, 0);
        }

#pragma unroll
        for (int r0 = 0; r0 < 4; r0++) {
            // sigmoid(x) = 1/(1+exp2(arg)), arg pre-scaled by -log2e (weights+bias+sc)
            float er = __builtin_amdgcn_exp2f(fmaf((float)a0[r0], sc[0], (float)gbuf[rb][0][r0]));
            float rg = __builtin_amdgcn_rcpf(1.f + er);
            float ez = __builtin_amdgcn_exp2f(fmaf((float)a1[r0], sc[1], (float)gbuf[rb][1][r0]));
            float zg = __builtin_amdgcn_rcpf(1.f + ez);
            // tanh(x) = 1 - 2/(1+exp2(x*2log2e)), operands pre-scaled by 2log2e
            float narg = fmaf(rg, fmaf((float)a2[r0], sc[2], bnv), (float)gbuf[rb][2][r0]);
            float en = __builtin_amdgcn_exp2f(narg);
            float ng = fmaf(-2.f, __builtin_amdgcn_rcpf(1.f + en), 1.f);
            float h  = fmaf(zg, hreg[r0] - ng, ng);
            hreg[r0] = h;
            hbuf[wbuf][(quad << 2) + r0][d] = (signed char)(int)__builtin_rintf(h * 127.f);
            go[(size_t)r0 * 256] = (__bf16)h;          // fire-and-forget (never waited)
        }
        gb += gstep;
        go += 8192;
        if (j + 2 < steps) gload(rb, gb + gstep);      // depth-2 prefetch into freed slot
        LDS_BARRIER();
    }
}

// ---------------- attention (online softmax over t<=i) ----------------
__global__ __launch_bounds__(512) void attn_kernel(
    const __bf16* __restrict__ revb, const __bf16* __restrict__ fwdb,
    const float* __restrict__ attn_w, const float* __restrict__ attn_bp,
    __bf16* __restrict__ ht)
{
    const int tid = threadIdx.x;
    const int w = tid >> 6, lane = tid & 63;
    const int wid = blockIdx.x * 8 + w;      // 2048 waves: one per (i,b)
    const int i = wid >> 5, b = wid & 31;
    const int d0 = lane * 4;

    float wf[4], wr[4];
#pragma unroll
    for (int q = 0; q < 4; q++) { wf[q] = attn_w[d0 + q]; wr[q] = attn_w[256 + d0 + q]; }
    const float ab = attn_bp[0];
    const __bf16* rp = revb + ((size_t)(i * (i + 1) / 2)) * 8192 + (size_t)b * 256 + d0;
    const __bf16* fp = fwdb + (size_t)b * 256 + d0;

    float mx = -1e30f, l = 0.f;
    float cf[4] = {0,0,0,0}, cr[4] = {0,0,0,0};
    bf16x4 rn = *(const bf16x4*)rp, fn = *(const bf16x4*)fp;
    for (int t = 0; t <= i; t++) {
        bf16x4 rv4 = rn, fv4 = fn;
        if (t < i) {                        // 1-deep prefetch
            rn = *(const bf16x4*)(rp + (size_t)(t + 1) * 8192);
            fn = *(const bf16x4*)(fp + (size_t)(t + 1) * 8192);
        }
        float rv[4], fv[4], s = 0.f;
#pragma unroll
        for (int q = 0; q < 4; q++) {
            rv[q] = (float)rv4[q]; fv[q] = (float)fv4[q];
            s += rv[q] * wr[q] + fv[q] * wf[q];
        }
#pragma unroll
        for (int off = 32; off > 0; off >>= 1) s += __shfl_xor(s, off);
        s += ab;
        float mn = fmaxf(mx, s);
        float scl = __expf(mx - mn);
        float p  = __expf(s - mn);
        l = l * scl + p;
#pragma unroll
        for (int q = 0; q < 4; q++) { cf[q] = cf[q] * scl + p * fv[q]; cr[q] = cr[q] * scl + p * rv[q]; }
        mx = mn;
    }
    float inv = __builtin_amdgcn_rcpf(l * (float)(i + 1));
    __bf16* hp = ht + (size_t)(i * 32 + b) * 1024 + d0;
    const __bf16* fl = fp + (size_t)i * 8192;
    const __bf16* rl = rp + (size_t)i * 8192;
#pragma unroll
    for (int q = 0; q < 4; q++) {
        hp[q]       = (__bf16)(cf[q] * inv);
        hp[256 + q] = (__bf16)(cr[q] * inv);
        hp[512 + q] = fl[q];
        hp[768 + q] = rl[q];
    }
}

// ---------------- launch ----------------
extern "C" void kernel_launch(void* const* d_in, const int* in_sizes, int n_in,
                              void* d_out, int out_size, void* d_ws, size_t ws_size,
                              hipStream_t stream) {
    const float* x      = (const float*)d_in[0];
    const float* W_emb  = (const float*)d_in[1];
    const float* b_emb  = (const float*)d_in[2];
    const float* Wih_f  = (const float*)d_in[3];
    const float* Whh_f  = (const float*)d_in[4];
    const float* bih_f  = (const float*)d_in[5];
    const float* bhh_f  = (const float*)d_in[6];
    const float* Wih_r  = (const float*)d_in[7];
    const float* Whh_r  = (const float*)d_in[8];
    const float* bih_r  = (const float*)d_in[9];
    const float* bhh_r  = (const float*)d_in[10];
    const float* attn_w = (const float*)d_in[11];
    const float* attn_b = (const float*)d_in[12];
    const float* W_ao   = (const float*)d_in[13];
    const float* b_ao   = (const float*)d_in[14];
    const float* W_o    = (const float*)d_in[15];
    const float* b_o    = (const float*)d_in[16];
    float* out = (float*)d_out;

    char* ws = (char*)d_ws;
    __bf16* pk_emb = (__bf16*)(ws + OFF_PK_EMB);
    __bf16* pk_ih  = (__bf16*)(ws + OFF_PK_IH);
    signed char* wq = (signed char*)(ws + OFF_WQ);
    float*  wsc    = (float*)(ws + OFF_WSC);
    __bf16* pk_ao  = (__bf16*)(ws + OFF_PK_AO);
    __bf16* pk_o   = (__bf16*)(ws + OFF_PK_O);
    __bf16* day    = (__bf16*)(ws + OFF_DAY);
    __bf16* Git    = (__bf16*)(ws + OFF_GIT);
    float*  bc     = (float*)(ws + OFF_BC);
    __bf16* revb   = (__bf16*)(ws + OFF_REV);
    __bf16* fwdb   = (__bf16*)(ws + OFF_FWD);
    __bf16* ht     = (__bf16*)(ws + OFF_HT);
    __bf16* tmp1   = (__bf16*)(ws + OFF_TMP1);

    pack_all<<<7616, 256, 0, stream>>>(W_emb, Wih_r, Wih_f, W_ao, W_o,
                                       pk_emb, pk_ih, pk_ao, pk_o);
    pack_hh_i8<<<1536, 64, 0, stream>>>(Whh_r, Whh_f, wq, wsc);
    prep_bias<<<6, 256, 0, stream>>>(bih_r, bhh_r, bih_f, bhh_f, bc);

    gemm_k<0, 4096, 8, 256, 256><<<dim3(32, 2), 256, 0, stream>>>(x, pk_emb, day, b_emb);
    gemm_k<1, 256, 4, 1536, 1536><<<dim3(32, 24), 256, 0, stream>>>(day, pk_ih, Git, bc);

    gru_recurrent<<<130, 1024, 0, stream>>>(wq, wsc, bhh_r, bhh_f, Git, revb, fwdb);

    attn_kernel<<<256, 512, 0, stream>>>(revb, fwdb, attn_w, attn_b, ht);

    gemm_k<2, 1024, 4, 256, 256><<<dim3(32, 4), 256, 0, stream>>>(ht, pk_ao, tmp1, b_ao);
    gemm_k<3, 256, 4, 942, 942><<<dim3(32, 15), 256, 0, stream>>>(tmp1, pk_o, out, b_o);
}

// Round 5
// 461.105 us; speedup vs baseline: 2.5135x; 2.5135x over previous
//
#include <hip/hip_runtime.h>
#include <hip/hip_bf16.h>

// Dipole: day-emb GEMM -> fwd GRU + 64 reverse GRUs -> masked softmax attention -> 2-layer head.
// T=64 B=32 D_IN=4096 D_DAY=H=256 D_OUT=942.
//
//  k1 pack_all      : repack GEMM weights to bf16 MFMA B-frag layout (Wih pre-scaled for exp2 gates).
//  k2 pack_hh_i8    : Whh -> int8 per-row-scaled B-frags (i8 16x16x64); also writes combined bias.
//  k3 gemm<0>       : day_emb = x @ W_emb^T + b_emb   (grid (32,4) -- R4's (32,2) regressed)
//  k4 gemm<1>       : Git = day_emb @ Wih^T + bias    (bf16 [dir][t][g][bh][d][b16]; transpose
//                     epilogue; layout gives the GRU fully-contiguous 512B/wave loads.
//                     R3 layout [d][b] caused 2x over-fetch + 770 line-touches/step)
//  k5 gru_recurrent : R3 structure (proven 127us): 128 rev + 2 fwd WGs, 1024thr/16 waves, int8
//                     MFMA, h-state fp32 in VGPR, int8 h via LDS dbuf, bf16 hist flushed every
//                     8 steps (batched stores stay OUT of the load-FIFO path -- R4 lesson),
//                     static gcur/gnxt prefetch regs (NO dynamic indexing -- R4 lesson).
//  k6 attn          : per-(i,b) wave online softmax; h_t = [c_f|c_r|fwd|rev_last]
//  k7 gemm<2>       : tmp = h_t @ W_ao^T + b_ao
//  k8 gemm<3>       : out = sigmoid(tmp @ W_o^T + b_o)

typedef __bf16 bf16x8 __attribute__((ext_vector_type(8)));
typedef __bf16 bf16x4 __attribute__((ext_vector_type(4)));
typedef float  f32x4  __attribute__((ext_vector_type(4)));
typedef int    int4v  __attribute__((ext_vector_type(4)));

static constexpr float NEG_L2E = -1.442695041f;   // -log2(e)
static constexpr float TWO_L2E =  2.885390082f;   //  2*log2(e)

// ---------------- workspace layout (bytes) ----------------
static constexpr size_t OFF_PK_EMB = 0;                        // 256x4096 bf16    = 2097152
static constexpr size_t OFF_PK_IH  = 2097152;                  // 1536x256 bf16    =  786432
static constexpr size_t OFF_WQ     = 2883584;                  // 2x768x256 int8   =  393216
static constexpr size_t OFF_WSC    = 3276800;                  // 1536 f32         =    6144
static constexpr size_t OFF_PK_AO  = 3670016;                  // 256x1024 bf16    =  524288
static constexpr size_t OFF_PK_O   = 4194304;                  // 960x256 bf16     =  491520
static constexpr size_t OFF_DAY    = 4685824;                  // 2048x256 bf16    = 1048576
static constexpr size_t OFF_GIT    = 5734400;                  // 2*64*3*2*256*16 bf16 = 6291456
static constexpr size_t OFF_BC     = 12025856;                 // 1536 f32         =    6144
static constexpr size_t OFF_REV    = 18317312;                 // 2080*32*256 bf16 = 34078720
static constexpr size_t OFF_FWD    = 52396032;                 // 64*32*256 bf16   = 1048576
static constexpr size_t OFF_HT     = 53444608;                 // 2048x1024 bf16   = 4194304
static constexpr size_t OFF_TMP1   = 57638912;                 // 2048x256 bf16    = 1048576

__device__ __forceinline__ float sigf(float x) {
    return __builtin_amdgcn_rcpf(1.f + __expf(-x));
}

// lgkmcnt-only barrier: does NOT drain vmcnt.
#define LDS_BARRIER() asm volatile("s_waitcnt lgkmcnt(0)\n\ts_barrier" ::: "memory")

// ---------------- bf16 weight packer (GEMM weights) ----------------
// frag layout: flat = ((nt*K32 + ks)*64 + lane)*8 + j holds W[nt*16+lane%16][ks*32+(lane/16)*8+j]
__global__ __launch_bounds__(256) void pack_all(
    const float* __restrict__ We,  const float* __restrict__ Wir, const float* __restrict__ Wif,
    const float* __restrict__ Wao, const float* __restrict__ Wo,
    __bf16* pe, __bf16* pi, __bf16* pao, __bf16* po)
{
    int b = blockIdx.x;
    const float* src; __bf16* dst; int Nsrc, k32l, b0; bool ih = false;
    if (b < 4096)      { src = We;  dst = pe;          Nsrc = 256; k32l = 7; b0 = 0;    }
    else if (b < 4864) { src = Wir; dst = pi;          Nsrc = 768; k32l = 3; b0 = 4096; ih = true; }
    else if (b < 5632) { src = Wif; dst = pi + 196608; Nsrc = 768; k32l = 3; b0 = 4864; ih = true; }
    else if (b < 6656) { src = Wao; dst = pao;         Nsrc = 256; k32l = 5; b0 = 5632; }
    else               { src = Wo;  dst = po;          Nsrc = 942; k32l = 3; b0 = 6656; }
    int e    = (b - b0) * 256 + threadIdx.x;
    int j    = e & 7;
    int lane = (e >> 3) & 63;
    int K32  = 1 << k32l;
    int K    = K32 << 5;
    int ks   = (e >> 9) & (K32 - 1);
    int nt   = e >> (9 + k32l);
    int n    = nt * 16 + (lane & 15);
    int k    = ks * 32 + ((lane >> 4) << 3) + j;
    float v  = (n < Nsrc) ? src[(size_t)n * K + k] : 0.f;
    if (ih) v *= (n < 512) ? NEG_L2E : TWO_L2E;   // exp2-form gate pre-scaling
    dst[e] = (__bf16)v;
}

// ---------------- Whh int8 packer + combined bias ----------------
// i8 16x16x64 B-frag: (n,k): lane = (n&15)|(((k>>4)&3)<<4), byte j = k&15;
// flat = dir*196608 + ((n>>4)*4 + (k>>6))*1024 + lane*16 + j.
// wscale[dir*768+n] = (rowmax/127^2) * gate-const (fully folded for the GRU).
// bc[dir*768+n]: rem<512 -> (bih+bhh)*NEG_L2E ; else bih*TWO_L2E.
__global__ __launch_bounds__(64) void pack_hh_i8(
    const float* __restrict__ Whr, const float* __restrict__ Whf,
    const float* __restrict__ bih_r, const float* __restrict__ bih_f,
    const float* __restrict__ bhh_r, const float* __restrict__ bhh_f,
    signed char* __restrict__ wq, float* __restrict__ wscale, float* __restrict__ bc)
{
    int b = blockIdx.x;               // 1536: dir*768 + n
    int dir = (b >= 768) ? 1 : 0;
    int n = b - dir * 768;
    const float* src = (dir ? Whf : Whr) + (size_t)n * 256;
    int t = threadIdx.x;
    float4 wv = ((const float4*)src)[t];
    float m = fmaxf(fmaxf(fabsf(wv.x), fabsf(wv.y)), fmaxf(fabsf(wv.z), fabsf(wv.w)));
#pragma unroll
    for (int off = 32; off > 0; off >>= 1) m = fmaxf(m, __shfl_xor(m, off));
    m = fmaxf(m, 1e-20f);
    float inv = 127.f / m;
    int q0 = (int)__builtin_rintf(wv.x * inv);
    int q1 = (int)__builtin_rintf(wv.y * inv);
    int q2 = (int)__builtin_rintf(wv.z * inv);
    int q3 = (int)__builtin_rintf(wv.w * inv);
    int pk = (q0 & 0xff) | ((q1 & 0xff) << 8) | ((q2 & 0xff) << 16) | ((q3 & 0xff) << 24);
    int dlane = (n & 15) | (((t >> 2) & 3) << 4);
    size_t byte = (size_t)dir * 196608 + ((size_t)(n >> 4) * 4 + (t >> 4)) * 1024
                + (size_t)dlane * 16 + (t & 3) * 4;
    *(int*)(wq + byte) = pk;
    if (t == 0) {
        float gc = (n < 512) ? NEG_L2E : TWO_L2E;
        wscale[b] = m * (1.f / 16129.f) * gc;
        const float* bi = dir ? bih_f : bih_r;
        const float* bh = dir ? bhh_f : bhh_r;
        bc[b] = (n < 512) ? (bi[n] + bh[n]) * NEG_L2E : bi[n] * TWO_L2E;
    }
}

// ---------------- generic MFMA GEMM: C[M x N] = A[M x K] @ W^T (+bias) ----------------
// MODE 0: A fp32, out bf16 row-major. MODE 1: A bf16, out bf16 Git (transposed epilogue).
// MODE 2: A bf16, out bf16 row-major. MODE 3: A bf16, out fp32 sigmoid masked to NREAL.
template<int MODE, int KDIM, int NTILES, int CSTRIDE, int NREAL>
__global__ __launch_bounds__(256) void gemm_k(
    const void* __restrict__ Ap, const __bf16* __restrict__ Bp, void* __restrict__ Cp,
    const float* __restrict__ bias)
{
    __shared__ __align__(16) __bf16 As[64][88];   // 88: 2-way banks in loop; 176B rows keep 16B align
    const int tid = threadIdx.x;
    const int w = tid >> 6, lane = tid & 63, c = lane & 15, quad = lane >> 4;
    const int mb = blockIdx.x, nb = blockIdx.y;
    constexpr int K32 = KDIM / 32;
    constexpr int NK  = KDIM / 64;

    f32x4 acc[NTILES];
#pragma unroll
    for (int nt = 0; nt < NTILES; nt++) acc[nt] = (f32x4){0.f, 0.f, 0.f, 0.f};

    const int row = tid >> 2, kp = (tid & 3) * 16;
    float4 pf[4]; uint4 pb[2];

    auto issue = [&](int kb) {
        if constexpr (MODE == 0) {
            const float* ap = (const float*)Ap + (size_t)(mb * 64 + row) * KDIM + kb * 64 + kp;
            pf[0] = ((const float4*)ap)[0]; pf[1] = ((const float4*)ap)[1];
            pf[2] = ((const float4*)ap)[2]; pf[3] = ((const float4*)ap)[3];
        } else {
            const __bf16* ap = (const __bf16*)Ap + (size_t)(mb * 64 + row) * KDIM + kb * 64 + kp;
            pb[0] = ((const uint4*)ap)[0]; pb[1] = ((const uint4*)ap)[1];
        }
    };
    auto commit = [&]() {
        if constexpr (MODE == 0) {
            __bf16 t[16];
#pragma unroll
            for (int q = 0; q < 4; q++) {
                t[q*4+0] = (__bf16)pf[q].x; t[q*4+1] = (__bf16)pf[q].y;
                t[q*4+2] = (__bf16)pf[q].z; t[q*4+3] = (__bf16)pf[q].w;
            }
            *(uint4*)&As[row][kp]     = *(uint4*)&t[0];
            *(uint4*)&As[row][kp + 8] = *(uint4*)&t[8];
        } else {
            *(uint4*)&As[row][kp]     = pb[0];
            *(uint4*)&As[row][kp + 8] = pb[1];
        }
    };

    issue(0);
    for (int kb = 0; kb < NK; kb++) {
        commit();
        __syncthreads();
        if (kb + 1 < NK) issue(kb + 1);
#pragma unroll
        for (int kk = 0; kk < 2; kk++) {
            bf16x8 a = *(const bf16x8*)&As[w * 16 + c][kk * 32 + quad * 8];
#pragma unroll
            for (int nt = 0; nt < NTILES; nt++) {
                bf16x8 bfr = *(const bf16x8*)(Bp +
                    ((size_t)((nb * NTILES + nt) * K32 + kb * 2 + kk) * 64 + lane) * 8);
                acc[nt] = __builtin_amdgcn_mfma_f32_16x16x32_bf16(a, bfr, acc[nt], 0, 0, 0);
            }
        }
        __syncthreads();
    }

    if constexpr (MODE == 1) {
        // transpose: acc -> As[n_local][m_local], then coalesced b128 stores into
        // Git[dir][t][g][bh][d][b16].
#pragma unroll
        for (int nt = 0; nt < NTILES; nt++) {
            float bv = bias[nb * 64 + nt * 16 + c];
#pragma unroll
            for (int r0 = 0; r0 < 4; r0++)
                As[nt * 16 + c][w * 16 + quad * 4 + r0] = (__bf16)(acc[nt][r0] + bv);
        }
        __syncthreads();
        const int dd = tid >> 2, bch = tid & 3;
        const int n = nb * 64 + dd;
        const int dir = (n >= 768) ? 1 : 0;
        const int rem = n - dir * 768;
        const int g = rem >> 8, dcol = rem & 255;
#pragma unroll
        for (int tl = 0; tl < 2; tl++) {
            uint4 v = *(const uint4*)&As[dd][tl * 32 + bch * 8];
            size_t off = (size_t)dir * 1572864 + (size_t)(mb * 2 + tl) * 24576
                       + ((size_t)((g * 2 + (bch >> 1)) * 256 + dcol)) * 16 + (bch & 1) * 8;
            *(uint4*)((__bf16*)Cp + off) = v;
        }
    } else {
#pragma unroll
        for (int nt = 0; nt < NTILES; nt++) {
            int n = nb * (NTILES * 16) + nt * 16 + c;
            float bv = (n < NREAL) ? bias[n] : 0.f;
#pragma unroll
            for (int r0 = 0; r0 < 4; r0++) {
                int m = mb * 64 + w * 16 + quad * 4 + r0;
                float v = acc[nt][r0] + bv;
                if constexpr (MODE == 0)      ((__bf16*)Cp)[(size_t)m * CSTRIDE + n] = (__bf16)v;
                else if constexpr (MODE == 2) ((__bf16*)Cp)[(size_t)m * CSTRIDE + n] = (__bf16)v;
                else { if (n < NREAL) ((float*)Cp)[(size_t)m * CSTRIDE + n] = sigf(v); }
            }
        }
    }
}

// ---------------- recurrent GRU kernel ----------------
// grid = 130 x 1024 (16 waves). bid 0/1: forward halves; bid 2..129: reverse, longest-first.
// Wave w owns 16 dims x 3 gates; Whh int8 frags (48 regs, AGPR-resident). h-state fp32 in
// VGPRs; int8 h broadcast via LDS dbuf; bf16 hist flushed every 8 steps with b128 stores.
__global__ __launch_bounds__(1024, 4) void gru_recurrent(
    const signed char* __restrict__ wq, const float* __restrict__ wscale,
    const float* __restrict__ bhh_r, const float* __restrict__ bhh_f,
    const __bf16* __restrict__ Git,
    __bf16* __restrict__ revb, __bf16* __restrict__ fwdb)
{
    __shared__ __align__(16) signed char hbuf[2][16][272];
    __shared__ __align__(16) __bf16 hist[8][4096];
    const int tid = threadIdx.x;
    const int w = tid >> 6, lane = tid & 63, c = lane & 15, quad = lane >> 4;
    const int bid = blockIdx.x;
    const bool isF = (bid < 2);
    const int ia = isF ? 63 : (63 - ((bid - 2) >> 1));
    const int bh = bid & 1;
    const int b0 = bh << 4;
    const int steps = ia + 1;
    const float* bhh = isF ? bhh_f : bhh_r;
    __bf16* outb = isF ? fwdb : (revb + ((size_t)(ia * (ia + 1) / 2)) * 8192);

    const int4v* pw = (const int4v*)(wq + (isF ? 196608 : 0));
    int4v bw[3][4];
#pragma unroll
    for (int g = 0; g < 3; g++)
#pragma unroll
        for (int ks = 0; ks < 4; ks++)
            bw[g][ks] = pw[(size_t)((g * 16 + w) * 4 + ks) * 64 + lane];
    const int d = (w << 4) + c;
    float sc[3];
#pragma unroll
    for (int g = 0; g < 3; g++) sc[g] = wscale[(isF ? 768 : 0) + g * 256 + d];
    const float bnv = bhh[512 + d] * TWO_L2E;

    float hreg[4] = {0.f, 0.f, 0.f, 0.f};
    for (int idx = tid; idx < 2 * 16 * 272 / 4; idx += 1024) ((int*)hbuf)[idx] = 0;
    __syncthreads();

    // Git[dir][t][g][bh][d][b16]: per-(wave,g) loads are 512B contiguous.
    const __bf16* gb = Git + (size_t)(isF ? 64 : ia) * 24576;
    const long gstep = isF ? 24576 : -24576;
    int loff[3];
#pragma unroll
    for (int g = 0; g < 3; g++) loff[g] = ((g * 2 + bh) * 256 + d) * 16 + (quad << 2);

    auto flush = [&](int jbase, int cnt) {
        int s = tid >> 7;
        if (s < cnt) {
            const uint4* src = (const uint4*)((const char*)&hist[s][0] + (tid & 127) * 64);
            uint4 v0 = src[0], v1 = src[1], v2 = src[2], v3 = src[3];
            uint4* dst = (uint4*)(outb + (size_t)(jbase + s) * 8192 + b0 * 256 + (tid & 127) * 32);
            dst[0] = v0; dst[1] = v1; dst[2] = v2; dst[3] = v3;
        }
    };

    bf16x4 gcur[3], gnxt[3];
#pragma unroll
    for (int g = 0; g < 3; g++) gcur[g] = *(const bf16x4*)(gb + loff[g]);

    for (int j = 0; j < steps; j++) {
        const int rb = j & 1, wbuf = rb ^ 1;

        if (j + 1 < steps) {
            const __bf16* gn = gb + gstep;
#pragma unroll
            for (int g = 0; g < 3; g++) gnxt[g] = *(const bf16x4*)(gn + loff[g]);
        }

        int4v a0 = {0,0,0,0}, a1 = {0,0,0,0}, a2 = {0,0,0,0};
#pragma unroll
        for (int ks = 0; ks < 4; ks++) {
            int4v av = *(const int4v*)&hbuf[rb][c][ks * 64 + quad * 16];
            a0 = __builtin_amdgcn_mfma_i32_16x16x64_i8(av, bw[0][ks], a0, 0, 0, 0);
            a1 = __builtin_amdgcn_mfma_i32_16x16x64_i8(av, bw[1][ks], a1, 0, 0, 0);
            a2 = __builtin_amdgcn_mfma_i32_16x16x64_i8(av, bw[2][ks], a2, 0, 0, 0);
        }

        const int hs = j & 7;
#pragma unroll
        for (int r0 = 0; r0 < 4; r0++) {
            float er = __builtin_amdgcn_exp2f(fmaf((float)a0[r0], sc[0], (float)gcur[0][r0]));
            float rg = __builtin_amdgcn_rcpf(1.f + er);
            float ez = __builtin_amdgcn_exp2f(fmaf((float)a1[r0], sc[1], (float)gcur[1][r0]));
            float zg = __builtin_amdgcn_rcpf(1.f + ez);
            float narg = fmaf(rg, fmaf((float)a2[r0], sc[2], bnv), (float)gcur[2][r0]);
            float en = __builtin_amdgcn_exp2f(narg);
            float ng = fmaf(-2.f, __builtin_amdgcn_rcpf(1.f + en), 1.f);
            float h  = fmaf(zg, hreg[r0] - ng, ng);
            hreg[r0] = h;
            int row = (quad << 2) + r0;
            hbuf[wbuf][row][d] = (signed char)(int)__builtin_rintf(h * 127.f);
            hist[hs][row * 256 + d] = (__bf16)h;
        }
        LDS_BARRIER();
        if (hs == 7) {                     // batched flush: stores out of the per-step FIFO path
            flush(j - 7, 8);
            LDS_BARRIER();
        }
        gb += gstep;
#pragma unroll
        for (int g = 0; g < 3; g++) gcur[g] = gnxt[g];
    }
    int rem = steps & 7;
    if (rem) flush(steps - rem, rem);
}

// ---------------- attention (online softmax over t<=i) ----------------
__global__ __launch_bounds__(512) void attn_kernel(
    const __bf16* __restrict__ revb, const __bf16* __restrict__ fwdb,
    const float* __restrict__ attn_w, const float* __restrict__ attn_bp,
    __bf16* __restrict__ ht)
{
    const int tid = threadIdx.x;
    const int w = tid >> 6, lane = tid & 63;
    const int wid = blockIdx.x * 8 + w;      // 2048 waves: one per (i,b)
    const int i = wid >> 5, b = wid & 31;
    const int d0 = lane * 4;

    float wf[4], wr[4];
#pragma unroll
    for (int q = 0; q < 4; q++) { wf[q] = attn_w[d0 + q]; wr[q] = attn_w[256 + d0 + q]; }
    const float ab = attn_bp[0];
    const __bf16* rp = revb + ((size_t)(i * (i + 1) / 2)) * 8192 + (size_t)b * 256 + d0;
    const __bf16* fp = fwdb + (size_t)b * 256 + d0;

    float mx = -1e30f, l = 0.f;
    float cf[4] = {0,0,0,0}, cr[4] = {0,0,0,0};
    bf16x4 rn = *(const bf16x4*)rp, fn = *(const bf16x4*)fp;
    for (int t = 0; t <= i; t++) {
        bf16x4 rv4 = rn, fv4 = fn;
        if (t < i) {
            rn = *(const bf16x4*)(rp + (size_t)(t + 1) * 8192);
            fn = *(const bf16x4*)(fp + (size_t)(t + 1) * 8192);
        }
        float rv[4], fv[4], s = 0.f;
#pragma unroll
        for (int q = 0; q < 4; q++) {
            rv[q] = (float)rv4[q]; fv[q] = (float)fv4[q];
            s += rv[q] * wr[q] + fv[q] * wf[q];
        }
#pragma unroll
        for (int off = 32; off > 0; off >>= 1) s += __shfl_xor(s, off);
        s += ab;
        float mn = fmaxf(mx, s);
        float scl = __expf(mx - mn);
        float p  = __expf(s - mn);
        l = l * scl + p;
#pragma unroll
        for (int q = 0; q < 4; q++) { cf[q] = cf[q] * scl + p * fv[q]; cr[q] = cr[q] * scl + p * rv[q]; }
        mx = mn;
    }
    float inv = __builtin_amdgcn_rcpf(l * (float)(i + 1));
    __bf16* hp = ht + (size_t)(i * 32 + b) * 1024 + d0;
    const __bf16* fl = fp + (size_t)i * 8192;
    const __bf16* rl = rp + (size_t)i * 8192;
#pragma unroll
    for (int q = 0; q < 4; q++) {
        hp[q]       = (__bf16)(cf[q] * inv);
        hp[256 + q] = (__bf16)(cr[q] * inv);
        hp[512 + q] = fl[q];
        hp[768 + q] = rl[q];
    }
}

// ---------------- launch ----------------
extern "C" void kernel_launch(void* const* d_in, const int* in_sizes, int n_in,
                              void* d_out, int out_size, void* d_ws, size_t ws_size,
                              hipStream_t stream) {
    const float* x      = (const float*)d_in[0];
    const float* W_emb  = (const float*)d_in[1];
    const float* b_emb  = (const float*)d_in[2];
    const float* Wih_f  = (const float*)d_in[3];
    const float* Whh_f  = (const float*)d_in[4];
    const float* bih_f  = (const float*)d_in[5];
    const float* bhh_f  = (const float*)d_in[6];
    const float* Wih_r  = (const float*)d_in[7];
    const float* Whh_r  = (const float*)d_in[8];
    const float* bih_r  = (const float*)d_in[9];
    const float* bhh_r  = (const float*)d_in[10];
    const float* attn_w = (const float*)d_in[11];
    const float* attn_b = (const float*)d_in[12];
    const float* W_ao   = (const float*)d_in[13];
    const float* b_ao   = (const float*)d_in[14];
    const float* W_o    = (const float*)d_in[15];
    const float* b_o    = (const float*)d_in[16];
    float* out = (float*)d_out;

    char* ws = (char*)d_ws;
    __bf16* pk_emb = (__bf16*)(ws + OFF_PK_EMB);
    __bf16* pk_ih  = (__bf16*)(ws + OFF_PK_IH);
    signed char* wq = (signed char*)(ws + OFF_WQ);
    float*  wsc    = (float*)(ws + OFF_WSC);
    __bf16* pk_ao  = (__bf16*)(ws + OFF_PK_AO);
    __bf16* pk_o   = (__bf16*)(ws + OFF_PK_O);
    __bf16* day    = (__bf16*)(ws + OFF_DAY);
    __bf16* Git    = (__bf16*)(ws + OFF_GIT);
    float*  bc     = (float*)(ws + OFF_BC);
    __bf16* revb   = (__bf16*)(ws + OFF_REV);
    __bf16* fwdb   = (__bf16*)(ws + OFF_FWD);
    __bf16* ht     = (__bf16*)(ws + OFF_HT);
    __bf16* tmp1   = (__bf16*)(ws + OFF_TMP1);

    pack_all<<<7616, 256, 0, stream>>>(W_emb, Wih_r, Wih_f, W_ao, W_o,
                                       pk_emb, pk_ih, pk_ao, pk_o);
    pack_hh_i8<<<1536, 64, 0, stream>>>(Whh_r, Whh_f, bih_r, bih_f, bhh_r, bhh_f,
                                        wq, wsc, bc);

    gemm_k<0, 4096, 4, 256, 256><<<dim3(32, 4), 256, 0, stream>>>(x, pk_emb, day, b_emb);
    gemm_k<1, 256, 4, 1536, 1536><<<dim3(32, 24), 256, 0, stream>>>(day, pk_ih, Git, bc);

    gru_recurrent<<<130, 1024, 0, stream>>>(wq, wsc, bhh_r, bhh_f, Git, revb, fwdb);

    attn_kernel<<<256, 512, 0, stream>>>(revb, fwdb, attn_w, attn_b, ht);

    gemm_k<2, 1024, 4, 256, 256><<<dim3(32, 4), 256, 0, stream>>>(ht, pk_ao, tmp1, b_ao);
    gemm_k<3, 256, 4, 942, 942><<<dim3(32, 15), 256, 0, stream>>>(tmp1, pk_o, out, b_o);
}

// Round 6
// 350.013 us; speedup vs baseline: 3.3113x; 1.3174x over previous
//
#include <hip/hip_runtime.h>
#include <hip/hip_bf16.h>

// Dipole: day-emb GEMM -> fwd GRU + 64 reverse GRUs -> masked softmax attention -> 2-layer head.
// T=64 B=32 D_IN=4096 D_DAY=H=256 D_OUT=942.
//
//  k1 pack_misc     : all bf16 weight-frag packing (8 elems/thread, coalesced) + x -> bf16.
//  k2 pack_hh_i8    : Whh -> int8 per-row-scaled B-frags (i8 16x16x64) + combined bias.
//  k3 gemm<2,4096>  : day_emb = xb @ W_emb^T + b_emb   (M=32 tiles, grid (64,4) = 256 WGs)
//  k4 gemm<1,256>   : Git = day_emb @ Wih^T + bias     (M=64 + transpose epilogue, proven)
//  k5 gru_recurrent : UNCHANGED from R5 (proven 119us; latency-bound lockstep structure)
//  k6 attn          : per-(i,b) wave online softmax
//  k7 gemm<2,1024>  : tmp = h_t @ W_ao^T + b_ao        (M=32, 256 WGs)
//  k8 gemm<3,256>   : out = sigmoid(tmp @ W_o^T + b_o) (M=32, 960 WGs)

typedef __bf16 bf16x8 __attribute__((ext_vector_type(8)));
typedef __bf16 bf16x4 __attribute__((ext_vector_type(4)));
typedef float  f32x4  __attribute__((ext_vector_type(4)));
typedef int    int4v  __attribute__((ext_vector_type(4)));

static constexpr float NEG_L2E = -1.442695041f;   // -log2(e)
static constexpr float TWO_L2E =  2.885390082f;   //  2*log2(e)

// ---------------- workspace layout (bytes) ----------------
static constexpr size_t OFF_PK_EMB = 0;                        // 256x4096 bf16    = 2097152
static constexpr size_t OFF_PK_IH  = 2097152;                  // 1536x256 bf16    =  786432
static constexpr size_t OFF_WQ     = 2883584;                  // 2x768x256 int8   =  393216
static constexpr size_t OFF_WSC    = 3276800;                  // 1536 f32         =    6144
static constexpr size_t OFF_PK_AO  = 3670016;                  // 256x1024 bf16    =  524288
static constexpr size_t OFF_PK_O   = 4194304;                  // 960x256 bf16     =  491520
static constexpr size_t OFF_DAY    = 4685824;                  // 2048x256 bf16    = 1048576
static constexpr size_t OFF_GIT    = 5734400;                  // 2*64*3*2*256*16 bf16 = 6291456
static constexpr size_t OFF_BC     = 12025856;                 // 1536 f32         =    6144
static constexpr size_t OFF_REV    = 18317312;                 // 2080*32*256 bf16 = 34078720
static constexpr size_t OFF_FWD    = 52396032;                 // 64*32*256 bf16   = 1048576
static constexpr size_t OFF_HT     = 53444608;                 // 2048x1024 bf16   = 4194304
static constexpr size_t OFF_TMP1   = 57638912;                 // 2048x256 bf16    = 1048576
// xb (2048x4096 bf16 = 16.7MB) aliases OFF_REV: dead before gru_recurrent writes rev.
static constexpr size_t OFF_XB     = OFF_REV;

__device__ __forceinline__ float sigf(float x) {
    return __builtin_amdgcn_rcpf(1.f + __expf(-x));
}

// lgkmcnt-only barrier: does NOT drain vmcnt.
#define LDS_BARRIER() asm volatile("s_waitcnt lgkmcnt(0)\n\ts_barrier" ::: "memory")

// ---------------- packer: all bf16 frag weights + x->bf16 ----------------
// frag layout: flat = ((nt*K32 + ks)*64 + lane)*8 + j holds W[nt*16+lane%16][ks*32+(lane/16)*8+j]
// 8 elems per thread: 32B contiguous read from one row, 16B frag write.
__global__ __launch_bounds__(256) void pack_misc(
    const float* __restrict__ We,  const float* __restrict__ Wir, const float* __restrict__ Wif,
    const float* __restrict__ Wao, const float* __restrict__ Wo,  const float* __restrict__ x,
    __bf16* pe, __bf16* pi, __bf16* pao, __bf16* po, __bf16* xb)
{
    int b = blockIdx.x;
    if (b >= 952) {                       // x -> bf16 (8 elems/thread)
        size_t base = ((size_t)(b - 952) * 256 + threadIdx.x) * 8;
        float4 v0 = *(const float4*)(x + base);
        float4 v1 = *(const float4*)(x + base + 4);
        bf16x8 o;
        o[0]=(__bf16)v0.x; o[1]=(__bf16)v0.y; o[2]=(__bf16)v0.z; o[3]=(__bf16)v0.w;
        o[4]=(__bf16)v1.x; o[5]=(__bf16)v1.y; o[6]=(__bf16)v1.z; o[7]=(__bf16)v1.w;
        *(bf16x8*)(xb + base) = o;
        return;
    }
    const float* src; __bf16* dst; int Nsrc, k32l, b0; bool ih = false;
    if (b < 512)      { src = We;  dst = pe;          Nsrc = 256; k32l = 7; b0 = 0;   }
    else if (b < 608) { src = Wir; dst = pi;          Nsrc = 768; k32l = 3; b0 = 512; ih = true; }
    else if (b < 704) { src = Wif; dst = pi + 196608; Nsrc = 768; k32l = 3; b0 = 608; ih = true; }
    else if (b < 832) { src = Wao; dst = pao;         Nsrc = 256; k32l = 5; b0 = 704; }
    else              { src = Wo;  dst = po;          Nsrc = 942; k32l = 3; b0 = 832; }
    int t8   = (b - b0) * 256 + threadIdx.x;
    int lane = t8 & 63;
    int K32  = 1 << k32l;
    int K    = K32 << 5;
    int ks   = (t8 >> 6) & (K32 - 1);
    int nt   = t8 >> (6 + k32l);
    int n    = nt * 16 + (lane & 15);
    int k0   = ks * 32 + ((lane >> 4) << 3);
    bf16x8 o;
    if (n < Nsrc) {
        const float* sp = src + (size_t)n * K + k0;
        float4 v0 = *(const float4*)sp;
        float4 v1 = *(const float4*)(sp + 4);
        float s = ih ? ((n < 512) ? NEG_L2E : TWO_L2E) : 1.f;
        o[0]=(__bf16)(v0.x*s); o[1]=(__bf16)(v0.y*s); o[2]=(__bf16)(v0.z*s); o[3]=(__bf16)(v0.w*s);
        o[4]=(__bf16)(v1.x*s); o[5]=(__bf16)(v1.y*s); o[6]=(__bf16)(v1.z*s); o[7]=(__bf16)(v1.w*s);
    } else {
#pragma unroll
        for (int q = 0; q < 8; q++) o[q] = (__bf16)0.f;
    }
    *(bf16x8*)(dst + (size_t)t8 * 8) = o;
}

// ---------------- Whh int8 packer + combined bias ----------------
__global__ __launch_bounds__(64) void pack_hh_i8(
    const float* __restrict__ Whr, const float* __restrict__ Whf,
    const float* __restrict__ bih_r, const float* __restrict__ bih_f,
    const float* __restrict__ bhh_r, const float* __restrict__ bhh_f,
    signed char* __restrict__ wq, float* __restrict__ wscale, float* __restrict__ bc)
{
    int b = blockIdx.x;               // 1536: dir*768 + n
    int dir = (b >= 768) ? 1 : 0;
    int n = b - dir * 768;
    const float* src = (dir ? Whf : Whr) + (size_t)n * 256;
    int t = threadIdx.x;
    float4 wv = ((const float4*)src)[t];
    float m = fmaxf(fmaxf(fabsf(wv.x), fabsf(wv.y)), fmaxf(fabsf(wv.z), fabsf(wv.w)));
#pragma unroll
    for (int off = 32; off > 0; off >>= 1) m = fmaxf(m, __shfl_xor(m, off));
    m = fmaxf(m, 1e-20f);
    float inv = 127.f / m;
    int q0 = (int)__builtin_rintf(wv.x * inv);
    int q1 = (int)__builtin_rintf(wv.y * inv);
    int q2 = (int)__builtin_rintf(wv.z * inv);
    int q3 = (int)__builtin_rintf(wv.w * inv);
    int pk = (q0 & 0xff) | ((q1 & 0xff) << 8) | ((q2 & 0xff) << 16) | ((q3 & 0xff) << 24);
    int dlane = (n & 15) | (((t >> 2) & 3) << 4);
    size_t byte = (size_t)dir * 196608 + ((size_t)(n >> 4) * 4 + (t >> 4)) * 1024
                + (size_t)dlane * 16 + (t & 3) * 4;
    *(int*)(wq + byte) = pk;
    if (t == 0) {
        float gc = (n < 512) ? NEG_L2E : TWO_L2E;
        wscale[b] = m * (1.f / 16129.f) * gc;
        const float* bi = dir ? bih_f : bih_r;
        const float* bh = dir ? bhh_f : bhh_r;
        bc[b] = (n < 512) ? (bi[n] + bh[n]) * NEG_L2E : bi[n] * TWO_L2E;
    }
}

// ---------------- generic MFMA GEMM: C[M x N] = A[M x K] @ W^T (+bias), A bf16 ----------------
// MR=64: wave w = row-tile w, all NTILES cols (required for MODE 1's transpose epilogue).
// MR=32: wave w = row-tile (w&1), col-half (w>>1) -> 2x the WGs, same total B traffic.
// MODE 1: out bf16 Git[dir][t][g][bh][d][b16] via LDS transpose. MODE 2: bf16 row-major.
// MODE 3: fp32 sigmoid masked to NREAL.
template<int MODE, int KDIM, int NTILES, int MR, int CSTRIDE, int NREAL>
__global__ __launch_bounds__(256) void gemm_k(
    const __bf16* __restrict__ Ap, const __bf16* __restrict__ Bp, void* __restrict__ Cp,
    const float* __restrict__ bias)
{
    __shared__ __align__(16) __bf16 As[MR][88];
    const int tid = threadIdx.x;
    const int w = tid >> 6, lane = tid & 63, c = lane & 15, quad = lane >> 4;
    const int mb = blockIdx.x, nb = blockIdx.y;
    constexpr int K32 = KDIM / 32;
    constexpr int NK  = KDIM / 64;
    constexpr int NT_W = (MR == 64) ? NTILES : NTILES / 2;
    constexpr int TPR  = (MR == 64) ? 4 : 8;        // threads per A row
    constexpr int EPT  = 64 / TPR;                  // elems per thread (16 or 8)
    const int wrow  = (MR == 64) ? w : (w & 1);
    const int ncol0 = (MR == 64) ? 0 : (w >> 1) * NT_W;

    f32x4 acc[NT_W];
#pragma unroll
    for (int nt = 0; nt < NT_W; nt++) acc[nt] = (f32x4){0.f, 0.f, 0.f, 0.f};

    const int row = tid / TPR, kp = (tid % TPR) * EPT;
    uint4 pb[EPT / 8];

    auto issue = [&](int kb) {
        const __bf16* ap = Ap + (size_t)(mb * MR + row) * KDIM + kb * 64 + kp;
        pb[0] = ((const uint4*)ap)[0];
        if constexpr (EPT == 16) pb[1] = ((const uint4*)ap)[1];
    };
    auto commit = [&]() {
        *(uint4*)&As[row][kp] = pb[0];
        if constexpr (EPT == 16) *(uint4*)&As[row][kp + 8] = pb[1];
    };

    issue(0);
    for (int kb = 0; kb < NK; kb++) {
        commit();
        __syncthreads();
        if (kb + 1 < NK) issue(kb + 1);
#pragma unroll
        for (int kk = 0; kk < 2; kk++) {
            bf16x8 a = *(const bf16x8*)&As[wrow * 16 + c][kk * 32 + quad * 8];
#pragma unroll
            for (int nt = 0; nt < NT_W; nt++) {
                bf16x8 bfr = *(const bf16x8*)(Bp +
                    ((size_t)((nb * NTILES + ncol0 + nt) * K32 + kb * 2 + kk) * 64 + lane) * 8);
                acc[nt] = __builtin_amdgcn_mfma_f32_16x16x32_bf16(a, bfr, acc[nt], 0, 0, 0);
            }
        }
        __syncthreads();
    }

    if constexpr (MODE == 1) {
        static_assert(MR == 64 && NTILES == 4, "MODE1 epilogue requires 64x64 tile");
#pragma unroll
        for (int nt = 0; nt < 4; nt++) {
            float bv = bias[nb * 64 + nt * 16 + c];
#pragma unroll
            for (int r0 = 0; r0 < 4; r0++)
                As[nt * 16 + c][w * 16 + quad * 4 + r0] = (__bf16)(acc[nt][r0] + bv);
        }
        __syncthreads();
        const int dd = tid >> 2, bch = tid & 3;
        const int n = nb * 64 + dd;
        const int dir = (n >= 768) ? 1 : 0;
        const int rem = n - dir * 768;
        const int g = rem >> 8, dcol = rem & 255;
#pragma unroll
        for (int tl = 0; tl < 2; tl++) {
            uint4 v = *(const uint4*)&As[dd][tl * 32 + bch * 8];
            size_t off = (size_t)dir * 1572864 + (size_t)(mb * 2 + tl) * 24576
                       + ((size_t)((g * 2 + (bch >> 1)) * 256 + dcol)) * 16 + (bch & 1) * 8;
            *(uint4*)((__bf16*)Cp + off) = v;
        }
    } else {
#pragma unroll
        for (int nt = 0; nt < NT_W; nt++) {
            int n = nb * (NTILES * 16) + (ncol0 + nt) * 16 + c;
            float bv = (n < NREAL) ? bias[n] : 0.f;
#pragma unroll
            for (int r0 = 0; r0 < 4; r0++) {
                int m = mb * MR + wrow * 16 + quad * 4 + r0;
                float v = acc[nt][r0] + bv;
                if constexpr (MODE == 2) ((__bf16*)Cp)[(size_t)m * CSTRIDE + n] = (__bf16)v;
                else { if (n < NREAL) ((float*)Cp)[(size_t)m * CSTRIDE + n] = sigf(v); }
            }
        }
    }
}

// ---------------- recurrent GRU kernel (UNCHANGED from R5 -- proven) ----------------
__global__ __launch_bounds__(1024, 4) void gru_recurrent(
    const signed char* __restrict__ wq, const float* __restrict__ wscale,
    const float* __restrict__ bhh_r, const float* __restrict__ bhh_f,
    const __bf16* __restrict__ Git,
    __bf16* __restrict__ revb, __bf16* __restrict__ fwdb)
{
    __shared__ __align__(16) signed char hbuf[2][16][272];
    __shared__ __align__(16) __bf16 hist[8][4096];
    const int tid = threadIdx.x;
    const int w = tid >> 6, lane = tid & 63, c = lane & 15, quad = lane >> 4;
    const int bid = blockIdx.x;
    const bool isF = (bid < 2);
    const int ia = isF ? 63 : (63 - ((bid - 2) >> 1));
    const int bh = bid & 1;
    const int b0 = bh << 4;
    const int steps = ia + 1;
    const float* bhh = isF ? bhh_f : bhh_r;
    __bf16* outb = isF ? fwdb : (revb + ((size_t)(ia * (ia + 1) / 2)) * 8192);

    const int4v* pw = (const int4v*)(wq + (isF ? 196608 : 0));
    int4v bw[3][4];
#pragma unroll
    for (int g = 0; g < 3; g++)
#pragma unroll
        for (int ks = 0; ks < 4; ks++)
            bw[g][ks] = pw[(size_t)((g * 16 + w) * 4 + ks) * 64 + lane];
    const int d = (w << 4) + c;
    float sc[3];
#pragma unroll
    for (int g = 0; g < 3; g++) sc[g] = wscale[(isF ? 768 : 0) + g * 256 + d];
    const float bnv = bhh[512 + d] * TWO_L2E;

    float hreg[4] = {0.f, 0.f, 0.f, 0.f};
    for (int idx = tid; idx < 2 * 16 * 272 / 4; idx += 1024) ((int*)hbuf)[idx] = 0;
    __syncthreads();

    const __bf16* gb = Git + (size_t)(isF ? 64 : ia) * 24576;
    const long gstep = isF ? 24576 : -24576;
    int loff[3];
#pragma unroll
    for (int g = 0; g < 3; g++) loff[g] = ((g * 2 + bh) * 256 + d) * 16 + (quad << 2);

    auto flush = [&](int jbase, int cnt) {
        int s = tid >> 7;
        if (s < cnt) {
            const uint4* src = (const uint4*)((const char*)&hist[s][0] + (tid & 127) * 64);
            uint4 v0 = src[0], v1 = src[1], v2 = src[2], v3 = src[3];
            uint4* dst = (uint4*)(outb + (size_t)(jbase + s) * 8192 + b0 * 256 + (tid & 127) * 32);
            dst[0] = v0; dst[1] = v1; dst[2] = v2; dst[3] = v3;
        }
    };

    bf16x4 gcur[3], gnxt[3];
#pragma unroll
    for (int g = 0; g < 3; g++) gcur[g] = *(const bf16x4*)(gb + loff[g]);

    for (int j = 0; j < steps; j++) {
        const int rb = j & 1, wbuf = rb ^ 1;

        if (j + 1 < steps) {
            const __bf16* gn = gb + gstep;
#pragma unroll
            for (int g = 0; g < 3; g++) gnxt[g] = *(const bf16x4*)(gn + loff[g]);
        }

        int4v a0 = {0,0,0,0}, a1 = {0,0,0,0}, a2 = {0,0,0,0};
#pragma unroll
        for (int ks = 0; ks < 4; ks++) {
            int4v av = *(const int4v*)&hbuf[rb][c][ks * 64 + quad * 16];
            a0 = __builtin_amdgcn_mfma_i32_16x16x64_i8(av, bw[0][ks], a0, 0, 0, 0);
            a1 = __builtin_amdgcn_mfma_i32_16x16x64_i8(av, bw[1][ks], a1, 0, 0, 0);
            a2 = __builtin_amdgcn_mfma_i32_16x16x64_i8(av, bw[2][ks], a2, 0, 0, 0);
        }

        const int hs = j & 7;
#pragma unroll
        for (int r0 = 0; r0 < 4; r0++) {
            float er = __builtin_amdgcn_exp2f(fmaf((float)a0[r0], sc[0], (float)gcur[0][r0]));
            float rg = __builtin_amdgcn_rcpf(1.f + er);
            float ez = __builtin_amdgcn_exp2f(fmaf((float)a1[r0], sc[1], (float)gcur[1][r0]));
            float zg = __builtin_amdgcn_rcpf(1.f + ez);
            float narg = fmaf(rg, fmaf((float)a2[r0], sc[2], bnv), (float)gcur[2][r0]);
            float en = __builtin_amdgcn_exp2f(narg);
            float ng = fmaf(-2.f, __builtin_amdgcn_rcpf(1.f + en), 1.f);
            float h  = fmaf(zg, hreg[r0] - ng, ng);
            hreg[r0] = h;
            int row = (quad << 2) + r0;
            hbuf[wbuf][row][d] = (signed char)(int)__builtin_rintf(h * 127.f);
            hist[hs][row * 256 + d] = (__bf16)h;
        }
        LDS_BARRIER();
        if (hs == 7) {
            flush(j - 7, 8);
            LDS_BARRIER();
        }
        gb += gstep;
#pragma unroll
        for (int g = 0; g < 3; g++) gcur[g] = gnxt[g];
    }
    int rem = steps & 7;
    if (rem) flush(steps - rem, rem);
}

// ---------------- attention (online softmax over t<=i) ----------------
__global__ __launch_bounds__(512) void attn_kernel(
    const __bf16* __restrict__ revb, const __bf16* __restrict__ fwdb,
    const float* __restrict__ attn_w, const float* __restrict__ attn_bp,
    __bf16* __restrict__ ht)
{
    const int tid = threadIdx.x;
    const int w = tid >> 6, lane = tid & 63;
    const int wid = blockIdx.x * 8 + w;      // 2048 waves: one per (i,b)
    const int i = wid >> 5, b = wid & 31;
    const int d0 = lane * 4;

    float wf[4], wr[4];
#pragma unroll
    for (int q = 0; q < 4; q++) { wf[q] = attn_w[d0 + q]; wr[q] = attn_w[256 + d0 + q]; }
    const float ab = attn_bp[0];
    const __bf16* rp = revb + ((size_t)(i * (i + 1) / 2)) * 8192 + (size_t)b * 256 + d0;
    const __bf16* fp = fwdb + (size_t)b * 256 + d0;

    float mx = -1e30f, l = 0.f;
    float cf[4] = {0,0,0,0}, cr[4] = {0,0,0,0};
    bf16x4 rn = *(const bf16x4*)rp, fn = *(const bf16x4*)fp;
    for (int t = 0; t <= i; t++) {
        bf16x4 rv4 = rn, fv4 = fn;
        if (t < i) {
            rn = *(const bf16x4*)(rp + (size_t)(t + 1) * 8192);
            fn = *(const bf16x4*)(fp + (size_t)(t + 1) * 8192);
        }
        float rv[4], fv[4], s = 0.f;
#pragma unroll
        for (int q = 0; q < 4; q++) {
            rv[q] = (float)rv4[q]; fv[q] = (float)fv4[q];
            s += rv[q] * wr[q] + fv[q] * wf[q];
        }
#pragma unroll
        for (int off = 32; off > 0; off >>= 1) s += __shfl_xor(s, off);
        s += ab;
        float mn = fmaxf(mx, s);
        float scl = __expf(mx - mn);
        float p  = __expf(s - mn);
        l = l * scl + p;
#pragma unroll
        for (int q = 0; q < 4; q++) { cf[q] = cf[q] * scl + p * fv[q]; cr[q] = cr[q] * scl + p * rv[q]; }
        mx = mn;
    }
    float inv = __builtin_amdgcn_rcpf(l * (float)(i + 1));
    __bf16* hp = ht + (size_t)(i * 32 + b) * 1024 + d0;
    const __bf16* fl = fp + (size_t)i * 8192;
    const __bf16* rl = rp + (size_t)i * 8192;
#pragma unroll
    for (int q = 0; q < 4; q++) {
        hp[q]       = (__bf16)(cf[q] * inv);
        hp[256 + q] = (__bf16)(cr[q] * inv);
        hp[512 + q] = fl[q];
        hp[768 + q] = rl[q];
    }
}

// ---------------- launch ----------------
extern "C" void kernel_launch(void* const* d_in, const int* in_sizes, int n_in,
                              void* d_out, int out_size, void* d_ws, size_t ws_size,
                              hipStream_t stream) {
    const float* x      = (const float*)d_in[0];
    const float* W_emb  = (const float*)d_in[1];
    const float* b_emb  = (const float*)d_in[2];
    const float* Wih_f  = (const float*)d_in[3];
    const float* Whh_f  = (const float*)d_in[4];
    const float* bih_f  = (const float*)d_in[5];
    const float* bhh_f  = (const float*)d_in[6];
    const float* Wih_r  = (const float*)d_in[7];
    const float* Whh_r  = (const float*)d_in[8];
    const float* bih_r  = (const float*)d_in[9];
    const float* bhh_r  = (const float*)d_in[10];
    const float* attn_w = (const float*)d_in[11];
    const float* attn_b = (const float*)d_in[12];
    const float* W_ao   = (const float*)d_in[13];
    const float* b_ao   = (const float*)d_in[14];
    const float* W_o    = (const float*)d_in[15];
    const float* b_o    = (const float*)d_in[16];
    float* out = (float*)d_out;

    char* ws = (char*)d_ws;
    __bf16* pk_emb = (__bf16*)(ws + OFF_PK_EMB);
    __bf16* pk_ih  = (__bf16*)(ws + OFF_PK_IH);
    signed char* wq = (signed char*)(ws + OFF_WQ);
    float*  wsc    = (float*)(ws + OFF_WSC);
    __bf16* pk_ao  = (__bf16*)(ws + OFF_PK_AO);
    __bf16* pk_o   = (__bf16*)(ws + OFF_PK_O);
    __bf16* day    = (__bf16*)(ws + OFF_DAY);
    __bf16* Git    = (__bf16*)(ws + OFF_GIT);
    float*  bc     = (float*)(ws + OFF_BC);
    __bf16* revb   = (__bf16*)(ws + OFF_REV);
    __bf16* fwdb   = (__bf16*)(ws + OFF_FWD);
    __bf16* ht     = (__bf16*)(ws + OFF_HT);
    __bf16* tmp1   = (__bf16*)(ws + OFF_TMP1);
    __bf16* xb     = (__bf16*)(ws + OFF_XB);     // aliases revb (dead until gru)

    pack_misc<<<5048, 256, 0, stream>>>(W_emb, Wih_r, Wih_f, W_ao, W_o, x,
                                        pk_emb, pk_ih, pk_ao, pk_o, xb);
    pack_hh_i8<<<1536, 64, 0, stream>>>(Whh_r, Whh_f, bih_r, bih_f, bhh_r, bhh_f,
                                        wq, wsc, bc);

    gemm_k<2, 4096, 4, 32, 256, 256><<<dim3(64, 4), 256, 0, stream>>>(xb, pk_emb, day, b_emb);
    gemm_k<1, 256, 4, 64, 1536, 1536><<<dim3(32, 24), 256, 0, stream>>>(day, pk_ih, Git, bc);

    gru_recurrent<<<130, 1024, 0, stream>>>(wq, wsc, bhh_r, bhh_f, Git, revb, fwdb);

    attn_kernel<<<256, 512, 0, stream>>>(revb, fwdb, attn_w, attn_b, ht);

    gemm_k<2, 1024, 4, 32, 256, 256><<<dim3(64, 4), 256, 0, stream>>>(ht, pk_ao, tmp1, b_ao);
    gemm_k<3, 256, 4, 32, 942, 942><<<dim3(64, 15), 256, 0, stream>>>(tmp1, pk_o, out, b_o);
}

// Round 7
// 350.011 us; speedup vs baseline: 3.3113x; 1.0000x over previous
//
#include <hip/hip_runtime.h>
#include <hip/hip_bf16.h>

// Dipole: day-emb GEMM -> fwd GRU + 64 reverse GRUs -> masked softmax attention -> 2-layer head.
// T=64 B=32 D_IN=4096 D_DAY=H=256 D_OUT=942.
//
//  k1 pack_misc     : bf16 weight-frag packing (8 elems/thread) + x -> bf16.
//  k2 pack_hh_i8    : Whh -> int8 per-row-scaled MFMA frags + combined bias.
//  k3 gemm<0,4096>  : day_emb = xb @ W_emb^T + b_emb        (M=32, grid (64,4))
//  k4 gemm<0,256>   : Gi = day_emb @ Wih^T + bias           (plain row-major [t*32+b][1536])
//  k5 gru_recurrent : FLIPPED mfma (C=[dim][batch]): lane owns 4 consecutive dims of one
//                     batch row -> contiguous b32/b64 writes; hist+flush deleted; 512thr/8
//                     waves (h B-frags wave-invariant -> LDS reads halve). Whh frags AGPR-parked.
//  k6 attn          : per-(i,b) wave online softmax
//  k7 gemm<0,1024>  : tmp = h_t @ W_ao^T + b_ao
//  k8 gemm<1,256>   : out = sigmoid(tmp @ W_o^T + b_o)
// All gemms: register double-buffer of B-frags (hide L2 latency at 1 WG/CU).

typedef __bf16 bf16x8 __attribute__((ext_vector_type(8)));
typedef __bf16 bf16x4 __attribute__((ext_vector_type(4)));
typedef float  f32x4  __attribute__((ext_vector_type(4)));
typedef int    int4v  __attribute__((ext_vector_type(4)));

static constexpr float NEG_L2E = -1.442695041f;   // -log2(e)
static constexpr float TWO_L2E =  2.885390082f;   //  2*log2(e)

// ---------------- workspace layout (bytes) ----------------
static constexpr size_t OFF_PK_EMB = 0;                        // 256x4096 bf16    = 2097152
static constexpr size_t OFF_PK_IH  = 2097152;                  // 1536x256 bf16    =  786432
static constexpr size_t OFF_WQ     = 2883584;                  // 2x768x256 int8   =  393216
static constexpr size_t OFF_WSC    = 3276800;                  // 1536 f32         =    6144
static constexpr size_t OFF_PK_AO  = 3670016;                  // 256x1024 bf16    =  524288
static constexpr size_t OFF_PK_O   = 4194304;                  // 960x256 bf16     =  491520
static constexpr size_t OFF_DAY    = 4685824;                  // 2048x256 bf16    = 1048576
static constexpr size_t OFF_GIT    = 5734400;                  // 2048x1536 bf16   = 6291456
static constexpr size_t OFF_BC     = 12025856;                 // 1536 f32         =    6144
static constexpr size_t OFF_REV    = 18317312;                 // 2080*32*256 bf16 = 34078720
static constexpr size_t OFF_FWD    = 52396032;                 // 64*32*256 bf16   = 1048576
static constexpr size_t OFF_HT     = 53444608;                 // 2048x1024 bf16   = 4194304
static constexpr size_t OFF_TMP1   = 57638912;                 // 2048x256 bf16    = 1048576
// xb (2048x4096 bf16 = 16.7MB) aliases OFF_REV: dead before gru_recurrent writes rev.
static constexpr size_t OFF_XB     = OFF_REV;

__device__ __forceinline__ float sigf(float x) {
    return __builtin_amdgcn_rcpf(1.f + __expf(-x));
}

// lgkmcnt-only barrier: does NOT drain vmcnt.
#define LDS_BARRIER() asm volatile("s_waitcnt lgkmcnt(0)\n\ts_barrier" ::: "memory")

// ---------------- packer: all bf16 frag weights + x->bf16 ----------------
// frag layout: flat = ((nt*K32 + ks)*64 + lane)*8 + j holds W[nt*16+lane%16][ks*32+(lane/16)*8+j]
__global__ __launch_bounds__(256) void pack_misc(
    const float* __restrict__ We,  const float* __restrict__ Wir, const float* __restrict__ Wif,
    const float* __restrict__ Wao, const float* __restrict__ Wo,  const float* __restrict__ x,
    __bf16* pe, __bf16* pi, __bf16* pao, __bf16* po, __bf16* xb)
{
    int b = blockIdx.x;
    if (b >= 952) {                       // x -> bf16 (8 elems/thread)
        size_t base = ((size_t)(b - 952) * 256 + threadIdx.x) * 8;
        float4 v0 = *(const float4*)(x + base);
        float4 v1 = *(const float4*)(x + base + 4);
        bf16x8 o;
        o[0]=(__bf16)v0.x; o[1]=(__bf16)v0.y; o[2]=(__bf16)v0.z; o[3]=(__bf16)v0.w;
        o[4]=(__bf16)v1.x; o[5]=(__bf16)v1.y; o[6]=(__bf16)v1.z; o[7]=(__bf16)v1.w;
        *(bf16x8*)(xb + base) = o;
        return;
    }
    const float* src; __bf16* dst; int Nsrc, k32l, b0; bool ih = false;
    if (b < 512)      { src = We;  dst = pe;          Nsrc = 256; k32l = 7; b0 = 0;   }
    else if (b < 608) { src = Wir; dst = pi;          Nsrc = 768; k32l = 3; b0 = 512; ih = true; }
    else if (b < 704) { src = Wif; dst = pi + 196608; Nsrc = 768; k32l = 3; b0 = 608; ih = true; }
    else if (b < 832) { src = Wao; dst = pao;         Nsrc = 256; k32l = 5; b0 = 704; }
    else              { src = Wo;  dst = po;          Nsrc = 942; k32l = 3; b0 = 832; }
    int t8   = (b - b0) * 256 + threadIdx.x;
    int lane = t8 & 63;
    int K32  = 1 << k32l;
    int K    = K32 << 5;
    int ks   = (t8 >> 6) & (K32 - 1);
    int nt   = t8 >> (6 + k32l);
    int n    = nt * 16 + (lane & 15);
    int k0   = ks * 32 + ((lane >> 4) << 3);
    bf16x8 o;
    if (n < Nsrc) {
        const float* sp = src + (size_t)n * K + k0;
        float4 v0 = *(const float4*)sp;
        float4 v1 = *(const float4*)(sp + 4);
        float s = ih ? ((n < 512) ? NEG_L2E : TWO_L2E) : 1.f;
        o[0]=(__bf16)(v0.x*s); o[1]=(__bf16)(v0.y*s); o[2]=(__bf16)(v0.z*s); o[3]=(__bf16)(v0.w*s);
        o[4]=(__bf16)(v1.x*s); o[5]=(__bf16)(v1.y*s); o[6]=(__bf16)(v1.z*s); o[7]=(__bf16)(v1.w*s);
    } else {
#pragma unroll
        for (int q = 0; q < 8; q++) o[q] = (__bf16)0.f;
    }
    *(bf16x8*)(dst + (size_t)t8 * 8) = o;
}

// ---------------- Whh int8 packer + combined bias ----------------
// i8 16x16x64 frag (A and B lane-maps are identical): (n,k): lane=(n&15)|(((k>>4)&3)<<4),
// byte j=k&15; flat = dir*196608 + ((n>>4)*4 + (k>>6))*1024 + lane*16 + j.
__global__ __launch_bounds__(64) void pack_hh_i8(
    const float* __restrict__ Whr, const float* __restrict__ Whf,
    const float* __restrict__ bih_r, const float* __restrict__ bih_f,
    const float* __restrict__ bhh_r, const float* __restrict__ bhh_f,
    signed char* __restrict__ wq, float* __restrict__ wscale, float* __restrict__ bc)
{
    int b = blockIdx.x;               // 1536: dir*768 + n
    int dir = (b >= 768) ? 1 : 0;
    int n = b - dir * 768;
    const float* src = (dir ? Whf : Whr) + (size_t)n * 256;
    int t = threadIdx.x;
    float4 wv = ((const float4*)src)[t];
    float m = fmaxf(fmaxf(fabsf(wv.x), fabsf(wv.y)), fmaxf(fabsf(wv.z), fabsf(wv.w)));
#pragma unroll
    for (int off = 32; off > 0; off >>= 1) m = fmaxf(m, __shfl_xor(m, off));
    m = fmaxf(m, 1e-20f);
    float inv = 127.f / m;
    int q0 = (int)__builtin_rintf(wv.x * inv);
    int q1 = (int)__builtin_rintf(wv.y * inv);
    int q2 = (int)__builtin_rintf(wv.z * inv);
    int q3 = (int)__builtin_rintf(wv.w * inv);
    int pk = (q0 & 0xff) | ((q1 & 0xff) << 8) | ((q2 & 0xff) << 16) | ((q3 & 0xff) << 24);
    int dlane = (n & 15) | (((t >> 2) & 3) << 4);
    size_t byte = (size_t)dir * 196608 + ((size_t)(n >> 4) * 4 + (t >> 4)) * 1024
                + (size_t)dlane * 16 + (t & 3) * 4;
    *(int*)(wq + byte) = pk;
    if (t == 0) {
        float gc = (n < 512) ? NEG_L2E : TWO_L2E;
        wscale[b] = m * (1.f / 16129.f) * gc;
        const float* bi = dir ? bih_f : bih_r;
        const float* bh = dir ? bhh_f : bhh_r;
        bc[b] = (n < 512) ? (bi[n] + bh[n]) * NEG_L2E : bi[n] * TWO_L2E;
    }
}

// ---------------- generic MFMA GEMM: C[M x N] = A[M x K] @ W^T (+bias), A bf16 ----------------
// M=32 tiles: wave w = row-tile (w&1), col-half (w>>1). Register double-buffer on B-frags.
// MODE 0: bf16 row-major. MODE 1: fp32 sigmoid masked to NREAL.
template<int MODE, int KDIM, int NTILES, int CSTRIDE, int NREAL>
__global__ __launch_bounds__(256) void gemm_k(
    const __bf16* __restrict__ Ap, const __bf16* __restrict__ Bp, void* __restrict__ Cp,
    const float* __restrict__ bias)
{
    __shared__ __align__(16) __bf16 As[32][88];
    const int tid = threadIdx.x;
    const int w = tid >> 6, lane = tid & 63, c = lane & 15, quad = lane >> 4;
    const int mb = blockIdx.x, nb = blockIdx.y;
    constexpr int K32 = KDIM / 32;
    constexpr int NK  = KDIM / 64;
    constexpr int NT_W = NTILES / 2;
    const int wrow = w & 1, ncol0 = (w >> 1) * NT_W;

    f32x4 acc[NT_W];
#pragma unroll
    for (int nt = 0; nt < NT_W; nt++) acc[nt] = (f32x4){0.f, 0.f, 0.f, 0.f};

    const int row = tid >> 3, kp = (tid & 7) * 8;
    uint4 pb;
    auto issue  = [&](int kb) { pb = *(const uint4*)(Ap + (size_t)(mb * 32 + row) * KDIM + kb * 64 + kp); };
    auto commit = [&]() { *(uint4*)&As[row][kp] = pb; };

    bf16x8 bcur[2][NT_W], bnxt[2][NT_W];
    auto loadB = [&](int kb, bf16x8 (&dst)[2][NT_W]) {
#pragma unroll
        for (int kk = 0; kk < 2; kk++)
#pragma unroll
            for (int nt = 0; nt < NT_W; nt++)
                dst[kk][nt] = *(const bf16x8*)(Bp +
                    ((size_t)((nb * NTILES + ncol0 + nt) * K32 + kb * 2 + kk) * 64 + lane) * 8);
    };

    issue(0);
    loadB(0, bcur);
    for (int kb = 0; kb < NK; kb++) {
        commit();
        __syncthreads();
        if (kb + 1 < NK) { issue(kb + 1); loadB(kb + 1, bnxt); }
#pragma unroll
        for (int kk = 0; kk < 2; kk++) {
            bf16x8 a = *(const bf16x8*)&As[wrow * 16 + c][kk * 32 + quad * 8];
#pragma unroll
            for (int nt = 0; nt < NT_W; nt++)
                acc[nt] = __builtin_amdgcn_mfma_f32_16x16x32_bf16(a, bcur[kk][nt], acc[nt], 0, 0, 0);
        }
        if (kb + 1 < NK) {
#pragma unroll
            for (int kk = 0; kk < 2; kk++)
#pragma unroll
                for (int nt = 0; nt < NT_W; nt++) bcur[kk][nt] = bnxt[kk][nt];
        }
        __syncthreads();
    }

#pragma unroll
    for (int nt = 0; nt < NT_W; nt++) {
        int n = nb * (NTILES * 16) + (ncol0 + nt) * 16 + c;
        float bv = (n < NREAL) ? bias[n] : 0.f;
#pragma unroll
        for (int r0 = 0; r0 < 4; r0++) {
            int m = mb * 32 + wrow * 16 + quad * 4 + r0;
            float v = acc[nt][r0] + bv;
            if constexpr (MODE == 0) ((__bf16*)Cp)[(size_t)m * CSTRIDE + n] = (__bf16)v;
            else { if (n < NREAL) ((float*)Cp)[(size_t)m * CSTRIDE + n] = sigf(v); }
        }
    }
}

// ---------------- recurrent GRU kernel (flipped: C = [dim][batch]) ----------------
// grid = 130 x 512 (8 waves). bid 0/1: forward halves; bid 2..129: reverse, longest-first.
// mfma(whh_frag, h_frag, .) -> C[m=dim][n=batch]: lane owns dims d0q..d0q+3 (per tile) of
// batch row c. All per-step writes contiguous: hbuf b32, global h b64. No hist/flush.
// Whh int8 frags: 96 regs (AGPR-parked; MFMA reads A from AGPR directly).
__global__ __launch_bounds__(512, 2) void gru_recurrent(
    const signed char* __restrict__ wq, const float* __restrict__ wscale,
    const float* __restrict__ bhh_r, const float* __restrict__ bhh_f,
    const __bf16* __restrict__ Gi,
    __bf16* __restrict__ revb, __bf16* __restrict__ fwdb)
{
    __shared__ __align__(16) signed char hbuf[2][16][272];   // [buf][batch][dim]
    const int tid = threadIdx.x;
    const int w = tid >> 6, lane = tid & 63, c = lane & 15, quad = lane >> 4;
    const int bid = blockIdx.x;
    const bool isF = (bid < 2);
    const int ia = isF ? 63 : (63 - ((bid - 2) >> 1));
    const int b0 = (bid & 1) << 4;
    const int steps = ia + 1;
    const float* bhh = isF ? bhh_f : bhh_r;
    __bf16* outb = isF ? fwdb : (revb + ((size_t)(ia * (ia + 1) / 2)) * 8192);
    const int dirb = isF ? 768 : 0;

    // Whh int8 A-frags: wave w owns dim-tiles 2w, 2w+1 per gate (96 regs -> AGPR)
    const int4v* pw = (const int4v*)(wq + (isF ? 196608 : 0));
    int4v bw[3][2][4];
#pragma unroll
    for (int g = 0; g < 3; g++)
#pragma unroll
        for (int tl = 0; tl < 2; tl++)
#pragma unroll
            for (int ks = 0; ks < 4; ks++)
                bw[g][tl][ks] = pw[(size_t)((g * 16 + 2 * w + tl) * 4 + ks) * 64 + lane];

    const int d0q = (w << 5) + (quad << 2);   // dims d0q+tl*16 .. +3
    f32x4 sc[3][2], bnv[2];
#pragma unroll
    for (int g = 0; g < 3; g++)
#pragma unroll
        for (int tl = 0; tl < 2; tl++)
            sc[g][tl] = *(const f32x4*)&wscale[dirb + g * 256 + d0q + tl * 16];
#pragma unroll
    for (int tl = 0; tl < 2; tl++) {
        f32x4 bv = *(const f32x4*)&bhh[512 + d0q + tl * 16];
#pragma unroll
        for (int q = 0; q < 4; q++) bnv[tl][q] = bv[q] * TWO_L2E;
    }

    float hreg[2][4] = {{0,0,0,0},{0,0,0,0}};
    for (int idx = tid; idx < 2 * 16 * 272 / 4; idx += 512) ((int*)hbuf)[idx] = 0;
    __syncthreads();

    // Gi row-major [t*32+b][1536]: lane reads 8B per (gate,tile) at its (batch,c) row
    const __bf16* grow = Gi + ((size_t)((isF ? 0 : ia) * 32 + b0 + c)) * 1536 + dirb + d0q;
    const long gstep = isF ? (32 * 1536) : -(32 * 1536);
    __bf16* go = outb + (size_t)(b0 + c) * 256 + d0q;

    bf16x4 gcur[3][2], gnxt[3][2];
#pragma unroll
    for (int g = 0; g < 3; g++)
#pragma unroll
        for (int tl = 0; tl < 2; tl++)
            gcur[g][tl] = *(const bf16x4*)(grow + g * 256 + tl * 16);

    for (int j = 0; j < steps; j++) {
        const int rb = j & 1, wbuf = rb ^ 1;
        const bool more = (j + 1 < steps);

        if (more) {            // prefetch next step's input gates (issued BEFORE stores)
            grow += gstep;
#pragma unroll
            for (int g = 0; g < 3; g++)
#pragma unroll
                for (int tl = 0; tl < 2; tl++)
                    gnxt[g][tl] = *(const bf16x4*)(grow + g * 256 + tl * 16);
        }

        int4v acc[3][2];
#pragma unroll
        for (int g = 0; g < 3; g++)
#pragma unroll
            for (int tl = 0; tl < 2; tl++) acc[g][tl] = (int4v){0, 0, 0, 0};
#pragma unroll
        for (int ks = 0; ks < 4; ks++) {
            int4v av = *(const int4v*)&hbuf[rb][c][ks * 64 + (quad << 4)];   // h B-frag (wave-invariant)
#pragma unroll
            for (int g = 0; g < 3; g++)
#pragma unroll
                for (int tl = 0; tl < 2; tl++)
                    acc[g][tl] = __builtin_amdgcn_mfma_i32_16x16x64_i8(bw[g][tl][ks], av,
                                                                       acc[g][tl], 0, 0, 0);
        }

#pragma unroll
        for (int tl = 0; tl < 2; tl++) {
            int pk = 0;
            bf16x4 hb;
#pragma unroll
            for (int r0 = 0; r0 < 4; r0++) {
                float er = __builtin_amdgcn_exp2f(fmaf((float)acc[0][tl][r0], sc[0][tl][r0],
                                                       (float)gcur[0][tl][r0]));
                float rg = __builtin_amdgcn_rcpf(1.f + er);
                float ez = __builtin_amdgcn_exp2f(fmaf((float)acc[1][tl][r0], sc[1][tl][r0],
                                                       (float)gcur[1][tl][r0]));
                float zg = __builtin_amdgcn_rcpf(1.f + ez);
                float narg = fmaf(rg, fmaf((float)acc[2][tl][r0], sc[2][tl][r0], bnv[tl][r0]),
                                  (float)gcur[2][tl][r0]);
                float en = __builtin_amdgcn_exp2f(narg);
                float ng = fmaf(-2.f, __builtin_amdgcn_rcpf(1.f + en), 1.f);
                float h  = fmaf(zg, hreg[tl][r0] - ng, ng);
                hreg[tl][r0] = h;
                int q = (int)__builtin_rintf(h * 127.f);
                pk |= (q & 0xff) << (8 * r0);
                hb[r0] = (__bf16)h;
            }
            *(int*)&hbuf[wbuf][c][d0q + tl * 16] = pk;        // contiguous int8x4
            *(bf16x4*)(go + tl * 16) = hb;                    // contiguous b64 global store
        }
        go += 8192;
        LDS_BARRIER();
        if (more) {
#pragma unroll
            for (int g = 0; g < 3; g++)
#pragma unroll
                for (int tl = 0; tl < 2; tl++) gcur[g][tl] = gnxt[g][tl];
        }
    }
}

// ---------------- attention (online softmax over t<=i) ----------------
__global__ __launch_bounds__(512) void attn_kernel(
    const __bf16* __restrict__ revb, const __bf16* __restrict__ fwdb,
    const float* __restrict__ attn_w, const float* __restrict__ attn_bp,
    __bf16* __restrict__ ht)
{
    const int tid = threadIdx.x;
    const int w = tid >> 6, lane = tid & 63;
    const int wid = blockIdx.x * 8 + w;      // 2048 waves: one per (i,b)
    const int i = wid >> 5, b = wid & 31;
    const int d0 = lane * 4;

    float wf[4], wr[4];
#pragma unroll
    for (int q = 0; q < 4; q++) { wf[q] = attn_w[d0 + q]; wr[q] = attn_w[256 + d0 + q]; }
    const float ab = attn_bp[0];
    const __bf16* rp = revb + ((size_t)(i * (i + 1) / 2)) * 8192 + (size_t)b * 256 + d0;
    const __bf16* fp = fwdb + (size_t)b * 256 + d0;

    float mx = -1e30f, l = 0.f;
    float cf[4] = {0,0,0,0}, cr[4] = {0,0,0,0};
    bf16x4 rn = *(const bf16x4*)rp, fn = *(const bf16x4*)fp;
    for (int t = 0; t <= i; t++) {
        bf16x4 rv4 = rn, fv4 = fn;
        if (t < i) {
            rn = *(const bf16x4*)(rp + (size_t)(t + 1) * 8192);
            fn = *(const bf16x4*)(fp + (size_t)(t + 1) * 8192);
        }
        float rv[4], fv[4], s = 0.f;
#pragma unroll
        for (int q = 0; q < 4; q++) {
            rv[q] = (float)rv4[q]; fv[q] = (float)fv4[q];
            s += rv[q] * wr[q] + fv[q] * wf[q];
        }
#pragma unroll
        for (int off = 32; off > 0; off >>= 1) s += __shfl_xor(s, off);
        s += ab;
        float mn = fmaxf(mx, s);
        float scl = __expf(mx - mn);
        float p  = __expf(s - mn);
        l = l * scl + p;
#pragma unroll
        for (int q = 0; q < 4; q++) { cf[q] = cf[q] * scl + p * fv[q]; cr[q] = cr[q] * scl + p * rv[q]; }
        mx = mn;
    }
    float inv = __builtin_amdgcn_rcpf(l * (float)(i + 1));
    __bf16* hp = ht + (size_t)(i * 32 + b) * 1024 + d0;
    const __bf16* fl = fp + (size_t)i * 8192;
    const __bf16* rl = rp + (size_t)i * 8192;
#pragma unroll
    for (int q = 0; q < 4; q++) {
        hp[q]       = (__bf16)(cf[q] * inv);
        hp[256 + q] = (__bf16)(cr[q] * inv);
        hp[512 + q] = fl[q];
        hp[768 + q] = rl[q];
    }
}

// ---------------- launch ----------------
extern "C" void kernel_launch(void* const* d_in, const int* in_sizes, int n_in,
                              void* d_out, int out_size, void* d_ws, size_t ws_size,
                              hipStream_t stream) {
    const float* x      = (const float*)d_in[0];
    const float* W_emb  = (const float*)d_in[1];
    const float* b_emb  = (const float*)d_in[2];
    const float* Wih_f  = (const float*)d_in[3];
    const float* Whh_f  = (const float*)d_in[4];
    const float* bih_f  = (const float*)d_in[5];
    const float* bhh_f  = (const float*)d_in[6];
    const float* Wih_r  = (const float*)d_in[7];
    const float* Whh_r  = (const float*)d_in[8];
    const float* bih_r  = (const float*)d_in[9];
    const float* bhh_r  = (const float*)d_in[10];
    const float* attn_w = (const float*)d_in[11];
    const float* attn_b = (const float*)d_in[12];
    const float* W_ao   = (const float*)d_in[13];
    const float* b_ao   = (const float*)d_in[14];
    const float* W_o    = (const float*)d_in[15];
    const float* b_o    = (const float*)d_in[16];
    float* out = (float*)d_out;

    char* ws = (char*)d_ws;
    __bf16* pk_emb = (__bf16*)(ws + OFF_PK_EMB);
    __bf16* pk_ih  = (__bf16*)(ws + OFF_PK_IH);
    signed char* wq = (signed char*)(ws + OFF_WQ);
    float*  wsc    = (float*)(ws + OFF_WSC);
    __bf16* pk_ao  = (__bf16*)(ws + OFF_PK_AO);
    __bf16* pk_o   = (__bf16*)(ws + OFF_PK_O);
    __bf16* day    = (__bf16*)(ws + OFF_DAY);
    __bf16* Gi     = (__bf16*)(ws + OFF_GIT);
    float*  bc     = (float*)(ws + OFF_BC);
    __bf16* revb   = (__bf16*)(ws + OFF_REV);
    __bf16* fwdb   = (__bf16*)(ws + OFF_FWD);
    __bf16* ht     = (__bf16*)(ws + OFF_HT);
    __bf16* tmp1   = (__bf16*)(ws + OFF_TMP1);
    __bf16* xb     = (__bf16*)(ws + OFF_XB);     // aliases revb (dead until gru)

    pack_misc<<<5048, 256, 0, stream>>>(W_emb, Wih_r, Wih_f, W_ao, W_o, x,
                                        pk_emb, pk_ih, pk_ao, pk_o, xb);
    pack_hh_i8<<<1536, 64, 0, stream>>>(Whh_r, Whh_f, bih_r, bih_f, bhh_r, bhh_f,
                                        wq, wsc, bc);

    gemm_k<0, 4096, 4, 256, 256><<<dim3(64, 4), 256, 0, stream>>>(xb, pk_emb, day, b_emb);
    gemm_k<0, 256, 4, 1536, 1536><<<dim3(64, 24), 256, 0, stream>>>(day, pk_ih, Gi, bc);

    gru_recurrent<<<130, 512, 0, stream>>>(wq, wsc, bhh_r, bhh_f, Gi, revb, fwdb);

    attn_kernel<<<256, 512, 0, stream>>>(revb, fwdb, attn_w, attn_b, ht);

    gemm_k<0, 1024, 4, 256, 256><<<dim3(64, 4), 256, 0, stream>>>(ht, pk_ao, tmp1, b_ao);
    gemm_k<1, 256, 4, 942, 942><<<dim3(64, 15), 256, 0, stream>>>(tmp1, pk_o, out, b_o);
}

// Round 8
// 324.882 us; speedup vs baseline: 3.5674x; 1.0773x over previous
//
#include <hip/hip_runtime.h>
#include <hip/hip_bf16.h>

// Dipole: day-emb GEMM -> fwd GRU + 64 reverse GRUs -> masked softmax attention -> 2-layer head.
// T=64 B=32 D_IN=4096 D_DAY=H=256 D_OUT=942.
//
//  k1 pack_misc     : bf16 weight-frag packing + x->bf16 + Whh int8 frags + combined bias.
//  k2 gemm<0,4096>  : day_emb = xb @ W_emb^T + b_emb        (M=32, grid (64,4))
//  k3 gemm<0,256>   : Gi = day_emb @ Wih^T + bias           (row-major [t*32+b][1536])
//  k4 gru_recurrent : HYBRID: R5's 16-wave shape (latency hiding) + R7's flipped mfma
//                     (C=[dim][batch] -> contiguous b32 LDS / b64 global writes, no hist).
//                     R7 lesson: 8 waves exposed the latency ladder (154us); 16 waves hide it.
//  k5 attn          : per-(i,b) wave online softmax
//  k6 gemm<0,1024>  : tmp = h_t @ W_ao^T + b_ao
//  k7 gemm<1,256>   : out = sigmoid(tmp @ W_o^T + b_o)
// All gemms: register double-buffer of B-frags (R7: non-GRU 231->195us).

typedef __bf16 bf16x8 __attribute__((ext_vector_type(8)));
typedef __bf16 bf16x4 __attribute__((ext_vector_type(4)));
typedef float  f32x4  __attribute__((ext_vector_type(4)));
typedef int    int4v  __attribute__((ext_vector_type(4)));

static constexpr float NEG_L2E = -1.442695041f;   // -log2(e)
static constexpr float TWO_L2E =  2.885390082f;   //  2*log2(e)

// ---------------- workspace layout (bytes) ----------------
static constexpr size_t OFF_PK_EMB = 0;                        // 256x4096 bf16    = 2097152
static constexpr size_t OFF_PK_IH  = 2097152;                  // 1536x256 bf16    =  786432
static constexpr size_t OFF_WQ     = 2883584;                  // 2x768x256 int8   =  393216
static constexpr size_t OFF_WSC    = 3276800;                  // 1536 f32         =    6144
static constexpr size_t OFF_PK_AO  = 3670016;                  // 256x1024 bf16    =  524288
static constexpr size_t OFF_PK_O   = 4194304;                  // 960x256 bf16     =  491520
static constexpr size_t OFF_DAY    = 4685824;                  // 2048x256 bf16    = 1048576
static constexpr size_t OFF_GIT    = 5734400;                  // 2048x1536 bf16   = 6291456
static constexpr size_t OFF_BC     = 12025856;                 // 1536 f32         =    6144
static constexpr size_t OFF_REV    = 18317312;                 // 2080*32*256 bf16 = 34078720
static constexpr size_t OFF_FWD    = 52396032;                 // 64*32*256 bf16   = 1048576
static constexpr size_t OFF_HT     = 53444608;                 // 2048x1024 bf16   = 4194304
static constexpr size_t OFF_TMP1   = 57638912;                 // 2048x256 bf16    = 1048576
// xb (2048x4096 bf16 = 16.7MB) aliases OFF_REV: dead before gru_recurrent writes rev.
static constexpr size_t OFF_XB     = OFF_REV;

__device__ __forceinline__ float sigf(float x) {
    return __builtin_amdgcn_rcpf(1.f + __expf(-x));
}

// lgkmcnt-only barrier: does NOT drain vmcnt.
#define LDS_BARRIER() asm volatile("s_waitcnt lgkmcnt(0)\n\ts_barrier" ::: "memory")

// ---------------- fused packer: bf16 frags + x->bf16 + Whh int8 + bias ----------------
// bf16 frag layout: flat = ((nt*K32+ks)*64+lane)*8+j holds W[nt*16+lane%16][ks*32+(lane/16)*8+j]
// i8 frag (A/B lane-symmetric): (n,k): lane=(n&15)|(((k>>4)&3)<<4), byte j=k&15;
//   flat = dir*196608 + ((n>>4)*4 + (k>>6))*1024 + lane*16 + j.
__global__ __launch_bounds__(256) void pack_misc(
    const float* __restrict__ We,  const float* __restrict__ Wir, const float* __restrict__ Wif,
    const float* __restrict__ Wao, const float* __restrict__ Wo,  const float* __restrict__ x,
    const float* __restrict__ Whr, const float* __restrict__ Whf,
    const float* __restrict__ bih_r, const float* __restrict__ bih_f,
    const float* __restrict__ bhh_r, const float* __restrict__ bhh_f,
    __bf16* pe, __bf16* pi, __bf16* pao, __bf16* po, __bf16* xb,
    signed char* __restrict__ wq, float* __restrict__ wscale, float* __restrict__ bc)
{
    int b = blockIdx.x;
    if (b >= 5048) {                      // Whh int8 pack: 4 rows per block (one per wave)
        int rowb = (b - 5048) * 4 + (threadIdx.x >> 6);   // 0..1535: dir*768 + n
        int t = threadIdx.x & 63;
        int dir = (rowb >= 768) ? 1 : 0;
        int n = rowb - dir * 768;
        const float* src = (dir ? Whf : Whr) + (size_t)n * 256;
        float4 wv = ((const float4*)src)[t];
        float m = fmaxf(fmaxf(fabsf(wv.x), fabsf(wv.y)), fmaxf(fabsf(wv.z), fabsf(wv.w)));
#pragma unroll
        for (int off = 32; off > 0; off >>= 1) m = fmaxf(m, __shfl_xor(m, off));
        m = fmaxf(m, 1e-20f);
        float inv = 127.f / m;
        int q0 = (int)__builtin_rintf(wv.x * inv);
        int q1 = (int)__builtin_rintf(wv.y * inv);
        int q2 = (int)__builtin_rintf(wv.z * inv);
        int q3 = (int)__builtin_rintf(wv.w * inv);
        int pk = (q0 & 0xff) | ((q1 & 0xff) << 8) | ((q2 & 0xff) << 16) | ((q3 & 0xff) << 24);
        int dlane = (n & 15) | (((t >> 2) & 3) << 4);
        size_t byte = (size_t)dir * 196608 + ((size_t)(n >> 4) * 4 + (t >> 4)) * 1024
                    + (size_t)dlane * 16 + (t & 3) * 4;
        *(int*)(wq + byte) = pk;
        if (t == 0) {
            float gc = (n < 512) ? NEG_L2E : TWO_L2E;
            wscale[rowb] = m * (1.f / 16129.f) * gc;
            const float* bi = dir ? bih_f : bih_r;
            const float* bh = dir ? bhh_f : bhh_r;
            bc[rowb] = (n < 512) ? (bi[n] + bh[n]) * NEG_L2E : bi[n] * TWO_L2E;
        }
        return;
    }
    if (b >= 952) {                       // x -> bf16 (8 elems/thread)
        size_t base = ((size_t)(b - 952) * 256 + threadIdx.x) * 8;
        float4 v0 = *(const float4*)(x + base);
        float4 v1 = *(const float4*)(x + base + 4);
        bf16x8 o;
        o[0]=(__bf16)v0.x; o[1]=(__bf16)v0.y; o[2]=(__bf16)v0.z; o[3]=(__bf16)v0.w;
        o[4]=(__bf16)v1.x; o[5]=(__bf16)v1.y; o[6]=(__bf16)v1.z; o[7]=(__bf16)v1.w;
        *(bf16x8*)(xb + base) = o;
        return;
    }
    const float* src; __bf16* dst; int Nsrc, k32l, b0; bool ih = false;
    if (b < 512)      { src = We;  dst = pe;          Nsrc = 256; k32l = 7; b0 = 0;   }
    else if (b < 608) { src = Wir; dst = pi;          Nsrc = 768; k32l = 3; b0 = 512; ih = true; }
    else if (b < 704) { src = Wif; dst = pi + 196608; Nsrc = 768; k32l = 3; b0 = 608; ih = true; }
    else if (b < 832) { src = Wao; dst = pao;         Nsrc = 256; k32l = 5; b0 = 704; }
    else              { src = Wo;  dst = po;          Nsrc = 942; k32l = 3; b0 = 832; }
    int t8   = (b - b0) * 256 + threadIdx.x;
    int lane = t8 & 63;
    int K32  = 1 << k32l;
    int K    = K32 << 5;
    int ks   = (t8 >> 6) & (K32 - 1);
    int nt   = t8 >> (6 + k32l);
    int n    = nt * 16 + (lane & 15);
    int k0   = ks * 32 + ((lane >> 4) << 3);
    bf16x8 o;
    if (n < Nsrc) {
        const float* sp = src + (size_t)n * K + k0;
        float4 v0 = *(const float4*)sp;
        float4 v1 = *(const float4*)(sp + 4);
        float s = ih ? ((n < 512) ? NEG_L2E : TWO_L2E) : 1.f;
        o[0]=(__bf16)(v0.x*s); o[1]=(__bf16)(v0.y*s); o[2]=(__bf16)(v0.z*s); o[3]=(__bf16)(v0.w*s);
        o[4]=(__bf16)(v1.x*s); o[5]=(__bf16)(v1.y*s); o[6]=(__bf16)(v1.z*s); o[7]=(__bf16)(v1.w*s);
    } else {
#pragma unroll
        for (int q = 0; q < 8; q++) o[q] = (__bf16)0.f;
    }
    *(bf16x8*)(dst + (size_t)t8 * 8) = o;
}

// ---------------- generic MFMA GEMM: C[M x N] = A[M x K] @ W^T (+bias), A bf16 ----------------
// M=32 tiles: wave w = row-tile (w&1), col-half (w>>1). Register double-buffer on B-frags.
// MODE 0: bf16 row-major. MODE 1: fp32 sigmoid masked to NREAL.
template<int MODE, int KDIM, int NTILES, int CSTRIDE, int NREAL>
__global__ __launch_bounds__(256) void gemm_k(
    const __bf16* __restrict__ Ap, const __bf16* __restrict__ Bp, void* __restrict__ Cp,
    const float* __restrict__ bias)
{
    __shared__ __align__(16) __bf16 As[32][88];
    const int tid = threadIdx.x;
    const int w = tid >> 6, lane = tid & 63, c = lane & 15, quad = lane >> 4;
    const int mb = blockIdx.x, nb = blockIdx.y;
    constexpr int K32 = KDIM / 32;
    constexpr int NK  = KDIM / 64;
    constexpr int NT_W = NTILES / 2;
    const int wrow = w & 1, ncol0 = (w >> 1) * NT_W;

    f32x4 acc[NT_W];
#pragma unroll
    for (int nt = 0; nt < NT_W; nt++) acc[nt] = (f32x4){0.f, 0.f, 0.f, 0.f};

    const int row = tid >> 3, kp = (tid & 7) * 8;
    uint4 pb;
    auto issue  = [&](int kb) { pb = *(const uint4*)(Ap + (size_t)(mb * 32 + row) * KDIM + kb * 64 + kp); };
    auto commit = [&]() { *(uint4*)&As[row][kp] = pb; };

    bf16x8 bcur[2][NT_W], bnxt[2][NT_W];
    auto loadB = [&](int kb, bf16x8 (&dst)[2][NT_W]) {
#pragma unroll
        for (int kk = 0; kk < 2; kk++)
#pragma unroll
            for (int nt = 0; nt < NT_W; nt++)
                dst[kk][nt] = *(const bf16x8*)(Bp +
                    ((size_t)((nb * NTILES + ncol0 + nt) * K32 + kb * 2 + kk) * 64 + lane) * 8);
    };

    issue(0);
    loadB(0, bcur);
    for (int kb = 0; kb < NK; kb++) {
        commit();
        __syncthreads();
        if (kb + 1 < NK) { issue(kb + 1); loadB(kb + 1, bnxt); }
#pragma unroll
        for (int kk = 0; kk < 2; kk++) {
            bf16x8 a = *(const bf16x8*)&As[wrow * 16 + c][kk * 32 + quad * 8];
#pragma unroll
            for (int nt = 0; nt < NT_W; nt++)
                acc[nt] = __builtin_amdgcn_mfma_f32_16x16x32_bf16(a, bcur[kk][nt], acc[nt], 0, 0, 0);
        }
        if (kb + 1 < NK) {
#pragma unroll
            for (int kk = 0; kk < 2; kk++)
#pragma unroll
                for (int nt = 0; nt < NT_W; nt++) bcur[kk][nt] = bnxt[kk][nt];
        }
        __syncthreads();
    }

#pragma unroll
    for (int nt = 0; nt < NT_W; nt++) {
        int n = nb * (NTILES * 16) + (ncol0 + nt) * 16 + c;
        float bv = (n < NREAL) ? bias[n] : 0.f;
#pragma unroll
        for (int r0 = 0; r0 < 4; r0++) {
            int m = mb * 32 + wrow * 16 + quad * 4 + r0;
            float v = acc[nt][r0] + bv;
            if constexpr (MODE == 0) ((__bf16*)Cp)[(size_t)m * CSTRIDE + n] = (__bf16)v;
            else { if (n < NREAL) ((float*)Cp)[(size_t)m * CSTRIDE + n] = sigf(v); }
        }
    }
}

// ---------------- recurrent GRU (hybrid: 16 waves, flipped C=[dim][batch]) ----------------
// grid = 130 x 1024 (16 waves). bid 0/1: forward halves; bid 2..129: reverse, longest-first.
// mfma(whh_frag, h_frag, .): wave w owns dims [16w,16w+16) x 3 gates (12 MFMA/step, 48 weight
// regs -> AGPR). Lane owns 4 consecutive dims of batch row c: hbuf write b32, global write b64
// fire-and-forget (issued AFTER the step's prefetch loads -> vmcnt waits never drain stores).
__global__ __launch_bounds__(1024, 4) void gru_recurrent(
    const signed char* __restrict__ wq, const float* __restrict__ wscale,
    const float* __restrict__ bhh_r, const float* __restrict__ bhh_f,
    const __bf16* __restrict__ Gi,
    __bf16* __restrict__ revb, __bf16* __restrict__ fwdb)
{
    __shared__ __align__(16) signed char hbuf[2][16][272];   // [buf][batch][dim]
    const int tid = threadIdx.x;
    const int w = tid >> 6, lane = tid & 63, c = lane & 15, quad = lane >> 4;
    const int bid = blockIdx.x;
    const bool isF = (bid < 2);
    const int ia = isF ? 63 : (63 - ((bid - 2) >> 1));
    const int b0 = (bid & 1) << 4;
    const int steps = ia + 1;
    const float* bhh = isF ? bhh_f : bhh_r;
    __bf16* outb = isF ? fwdb : (revb + ((size_t)(ia * (ia + 1) / 2)) * 8192);
    const int dirb = isF ? 768 : 0;

    // Whh int8 A-frags: wave w owns m-tile g*16+w per gate (48 regs -> AGPR)
    const int4v* pw = (const int4v*)(wq + (isF ? 196608 : 0));
    int4v bw[3][4];
#pragma unroll
    for (int g = 0; g < 3; g++)
#pragma unroll
        for (int ks = 0; ks < 4; ks++)
            bw[g][ks] = pw[(size_t)((g * 16 + w) * 4 + ks) * 64 + lane];

    const int dq = (w << 4) + (quad << 2);   // lane's dim base: 4 consecutive dims
    f32x4 sc[3];
#pragma unroll
    for (int g = 0; g < 3; g++) sc[g] = *(const f32x4*)&wscale[dirb + g * 256 + dq];
    f32x4 bnv = *(const f32x4*)&bhh[512 + dq];
#pragma unroll
    for (int q = 0; q < 4; q++) bnv[q] *= TWO_L2E;

    float hreg[4] = {0.f, 0.f, 0.f, 0.f};
    for (int idx = tid; idx < 2 * 16 * 272 / 4; idx += 1024) ((int*)hbuf)[idx] = 0;
    __syncthreads();

    // Gi row-major [t*32+b][1536]: lane reads 8B per gate at its (batch,dim) spot
    const __bf16* grow = Gi + (size_t)((isF ? 0 : ia) * 32 + b0 + c) * 1536 + dirb + dq;
    const long gstep = isF ? (32 * 1536) : -(32 * 1536);
    __bf16* go = outb + (size_t)(b0 + c) * 256 + dq;

    bf16x4 gcur[3], gnxt[3];
#pragma unroll
    for (int g = 0; g < 3; g++) gcur[g] = *(const bf16x4*)(grow + g * 256);

    for (int j = 0; j < steps; j++) {
        const int rb = j & 1, wbuf = rb ^ 1;
        const bool more = (j + 1 < steps);

        if (more) {            // prefetch next step's input gates (BEFORE this step's stores)
            grow += gstep;
#pragma unroll
            for (int g = 0; g < 3; g++) gnxt[g] = *(const bf16x4*)(grow + g * 256);
        }

        int4v a0 = {0,0,0,0}, a1 = {0,0,0,0}, a2 = {0,0,0,0};
#pragma unroll
        for (int ks = 0; ks < 4; ks++) {
            int4v av = *(const int4v*)&hbuf[rb][c][ks * 64 + (quad << 4)];  // h B-frag
            a0 = __builtin_amdgcn_mfma_i32_16x16x64_i8(bw[0][ks], av, a0, 0, 0, 0);
            a1 = __builtin_amdgcn_mfma_i32_16x16x64_i8(bw[1][ks], av, a1, 0, 0, 0);
            a2 = __builtin_amdgcn_mfma_i32_16x16x64_i8(bw[2][ks], av, a2, 0, 0, 0);
        }

        int pk = 0;
        bf16x4 hb;
#pragma unroll
        for (int r0 = 0; r0 < 4; r0++) {
            float er = __builtin_amdgcn_exp2f(fmaf((float)a0[r0], sc[0][r0], (float)gcur[0][r0]));
            float rg = __builtin_amdgcn_rcpf(1.f + er);
            float ez = __builtin_amdgcn_exp2f(fmaf((float)a1[r0], sc[1][r0], (float)gcur[1][r0]));
            float zg = __builtin_amdgcn_rcpf(1.f + ez);
            float narg = fmaf(rg, fmaf((float)a2[r0], sc[2][r0], bnv[r0]), (float)gcur[2][r0]);
            float en = __builtin_amdgcn_exp2f(narg);
            float ng = fmaf(-2.f, __builtin_amdgcn_rcpf(1.f + en), 1.f);
            float h  = fmaf(zg, hreg[r0] - ng, ng);
            hreg[r0] = h;
            int q = (int)__builtin_rintf(h * 127.f);
            pk |= (q & 0xff) << (8 * r0);
            hb[r0] = (__bf16)h;
        }
        *(int*)&hbuf[wbuf][c][dq] = pk;    // contiguous int8x4 (2-way banks: free)
        *(bf16x4*)go = hb;                 // contiguous b64 global, fire-and-forget
        go += 8192;
        LDS_BARRIER();
        if (more) {
#pragma unroll
            for (int g = 0; g < 3; g++) gcur[g] = gnxt[g];
        }
    }
}

// ---------------- attention (online softmax over t<=i) ----------------
__global__ __launch_bounds__(512) void attn_kernel(
    const __bf16* __restrict__ revb, const __bf16* __restrict__ fwdb,
    const float* __restrict__ attn_w, const float* __restrict__ attn_bp,
    __bf16* __restrict__ ht)
{
    const int tid = threadIdx.x;
    const int w = tid >> 6, lane = tid & 63;
    const int wid = blockIdx.x * 8 + w;      // 2048 waves: one per (i,b)
    const int i = wid >> 5, b = wid & 31;
    const int d0 = lane * 4;

    float wf[4], wr[4];
#pragma unroll
    for (int q = 0; q < 4; q++) { wf[q] = attn_w[d0 + q]; wr[q] = attn_w[256 + d0 + q]; }
    const float ab = attn_bp[0];
    const __bf16* rp = revb + ((size_t)(i * (i + 1) / 2)) * 8192 + (size_t)b * 256 + d0;
    const __bf16* fp = fwdb + (size_t)b * 256 + d0;

    float mx = -1e30f, l = 0.f;
    float cf[4] = {0,0,0,0}, cr[4] = {0,0,0,0};
    bf16x4 rn = *(const bf16x4*)rp, fn = *(const bf16x4*)fp;
    for (int t = 0; t <= i; t++) {
        bf16x4 rv4 = rn, fv4 = fn;
        if (t < i) {
            rn = *(const bf16x4*)(rp + (size_t)(t + 1) * 8192);
            fn = *(const bf16x4*)(fp + (size_t)(t + 1) * 8192);
        }
        float rv[4], fv[4], s = 0.f;
#pragma unroll
        for (int q = 0; q < 4; q++) {
            rv[q] = (float)rv4[q]; fv[q] = (float)fv4[q];
            s += rv[q] * wr[q] + fv[q] * wf[q];
        }
#pragma unroll
        for (int off = 32; off > 0; off >>= 1) s += __shfl_xor(s, off);
        s += ab;
        float mn = fmaxf(mx, s);
        float scl = __expf(mx - mn);
        float p  = __expf(s - mn);
        l = l * scl + p;
#pragma unroll
        for (int q = 0; q < 4; q++) { cf[q] = cf[q] * scl + p * fv[q]; cr[q] = cr[q] * scl + p * rv[q]; }
        mx = mn;
    }
    float inv = __builtin_amdgcn_rcpf(l * (float)(i + 1));
    __bf16* hp = ht + (size_t)(i * 32 + b) * 1024 + d0;
    const __bf16* fl = fp + (size_t)i * 8192;
    const __bf16* rl = rp + (size_t)i * 8192;
#pragma unroll
    for (int q = 0; q < 4; q++) {
        hp[q]       = (__bf16)(cf[q] * inv);
        hp[256 + q] = (__bf16)(cr[q] * inv);
        hp[512 + q] = fl[q];
        hp[768 + q] = rl[q];
    }
}

// ---------------- launch ----------------
extern "C" void kernel_launch(void* const* d_in, const int* in_sizes, int n_in,
                              void* d_out, int out_size, void* d_ws, size_t ws_size,
                              hipStream_t stream) {
    const float* x      = (const float*)d_in[0];
    const float* W_emb  = (const float*)d_in[1];
    const float* b_emb  = (const float*)d_in[2];
    const float* Wih_f  = (const float*)d_in[3];
    const float* Whh_f  = (const float*)d_in[4];
    const float* bih_f  = (const float*)d_in[5];
    const float* bhh_f  = (const float*)d_in[6];
    const float* Wih_r  = (const float*)d_in[7];
    const float* Whh_r  = (const float*)d_in[8];
    const float* bih_r  = (const float*)d_in[9];
    const float* bhh_r  = (const float*)d_in[10];
    const float* attn_w = (const float*)d_in[11];
    const float* attn_b = (const float*)d_in[12];
    const float* W_ao   = (const float*)d_in[13];
    const float* b_ao   = (const float*)d_in[14];
    const float* W_o    = (const float*)d_in[15];
    const float* b_o    = (const float*)d_in[16];
    float* out = (float*)d_out;

    char* ws = (char*)d_ws;
    __bf16* pk_emb = (__bf16*)(ws + OFF_PK_EMB);
    __bf16* pk_ih  = (__bf16*)(ws + OFF_PK_IH);
    signed char* wq = (signed char*)(ws + OFF_WQ);
    float*  wsc    = (float*)(ws + OFF_WSC);
    __bf16* pk_ao  = (__bf16*)(ws + OFF_PK_AO);
    __bf16* pk_o   = (__bf16*)(ws + OFF_PK_O);
    __bf16* day    = (__bf16*)(ws + OFF_DAY);
    __bf16* Gi     = (__bf16*)(ws + OFF_GIT);
    float*  bc     = (float*)(ws + OFF_BC);
    __bf16* revb   = (__bf16*)(ws + OFF_REV);
    __bf16* fwdb   = (__bf16*)(ws + OFF_FWD);
    __bf16* ht     = (__bf16*)(ws + OFF_HT);
    __bf16* tmp1   = (__bf16*)(ws + OFF_TMP1);
    __bf16* xb     = (__bf16*)(ws + OFF_XB);     // aliases revb (dead until gru)

    pack_misc<<<5432, 256, 0, stream>>>(W_emb, Wih_r, Wih_f, W_ao, W_o, x,
                                        Whh_r, Whh_f, bih_r, bih_f, bhh_r, bhh_f,
                                        pk_emb, pk_ih, pk_ao, pk_o, xb, wq, wsc, bc);

    gemm_k<0, 4096, 4, 256, 256><<<dim3(64, 4), 256, 0, stream>>>(xb, pk_emb, day, b_emb);
    gemm_k<0, 256, 4, 1536, 1536><<<dim3(64, 24), 256, 0, stream>>>(day, pk_ih, Gi, bc);

    gru_recurrent<<<130, 1024, 0, stream>>>(wq, wsc, bhh_r, bhh_f, Gi, revb, fwdb);

    attn_kernel<<<256, 512, 0, stream>>>(revb, fwdb, attn_w, attn_b, ht);

    gemm_k<0, 1024, 4, 256, 256><<<dim3(64, 4), 256, 0, stream>>>(ht, pk_ao, tmp1, b_ao);
    gemm_k<1, 256, 4, 942, 942><<<dim3(64, 15), 256, 0, stream>>>(tmp1, pk_o, out, b_o);
}